// Round 2
// baseline (1424.714 us; speedup 1.0000x reference)
//
#include <hip/hip_runtime.h>
#include <hip/hip_bf16.h>
#include <math.h>

#define IN_DIM  128
#define HID     64
#define H1      4
#define H2      2
#define OUT_DIM 64
#define D1      256   // H1*HID
#define D2      128   // H2*OUT_DIM
#define LRELU   0.2f
#define LN_EPS  1e-5f

// ---------------- edge_index dtype probe ----------------
// If the harness kept int64 edge_index, the odd int32 words of the src row
// are high halves of small non-negative values -> all zero. For int32 data
// they are random node ids (all-zero probability ~(2e-5)^8 ~ 0).
__global__ void detect_i64_kernel(const int* __restrict__ ei, int* __restrict__ flag)
{
    int any_odd_nonzero = 0;
    #pragma unroll
    for (int k = 1; k < 16; k += 2) any_odd_nonzero |= (ei[k] != 0);
    *flag = any_odd_nonzero ? 0 : 1;
}

// ---------------- GEMM1: h1 = x @ W1, fused attention logits ----------------
// block = 256 threads, 8 nodes per block. Each thread owns one output column.
__global__ __launch_bounds__(256) void gemm1_kernel(
    const float* __restrict__ x,      // [N,128] f32
    const float* __restrict__ W1,     // [128,256] f32
    const float* __restrict__ att_s,  // [256] (= [4,64] flat)
    const float* __restrict__ att_d,  // [256]
    float* __restrict__ h1,           // [N,256]
    float* __restrict__ al_s,         // [N,4]
    float* __restrict__ al_d,         // [N,4]
    int N)
{
    __shared__ float xs[8][IN_DIM];
    const int n0 = blockIdx.x * 8;
    const int tid = threadIdx.x;
    const int nrem = N - n0;

    for (int i = tid; i < 8 * IN_DIM; i += 256) {
        int r = i >> 7, k = i & 127;
        xs[r][k] = (r < nrem) ? x[(size_t)(n0 + r) * IN_DIM + k] : 0.f;
    }
    __syncthreads();

    float acc[8] = {0.f,0.f,0.f,0.f,0.f,0.f,0.f,0.f};
    for (int k = 0; k < IN_DIM; ++k) {
        float wk = W1[k * D1 + tid];
        #pragma unroll
        for (int r = 0; r < 8; ++r) acc[r] += xs[r][k] * wk;
    }

    #pragma unroll
    for (int r = 0; r < 8; ++r)
        if (r < nrem) h1[(size_t)(n0 + r) * D1 + tid] = acc[r];

    // attention logits: wave w (64 lanes) == head w; reduce over channels
    const float as_w = att_s[tid];
    const float ad_w = att_d[tid];
    const int lane = tid & 63, head = tid >> 6;
    #pragma unroll
    for (int r = 0; r < 8; ++r) {
        float ps = acc[r] * as_w;
        float pd = acc[r] * ad_w;
        for (int off = 32; off > 0; off >>= 1) {
            ps += __shfl_down(ps, off);
            pd += __shfl_down(pd, off);
        }
        if (lane == 0 && r < nrem) {
            al_s[(size_t)(n0 + r) * H1 + head] = ps;
            al_d[(size_t)(n0 + r) * H1 + head] = pd;
        }
    }
}

// ---------------- GEMM2: h2 = hmid @ W2, fused attention logits ----------------
__global__ __launch_bounds__(128) void gemm2_kernel(
    const float* __restrict__ hmid,   // [N,256] f32
    const float* __restrict__ W2,     // [256,128] f32
    const float* __restrict__ att_s,  // [128]
    const float* __restrict__ att_d,  // [128]
    float* __restrict__ h2,           // [N,128]
    float* __restrict__ al_s,         // [N,2]
    float* __restrict__ al_d,         // [N,2]
    int N)
{
    __shared__ float xs[8][D1];
    const int n0 = blockIdx.x * 8;
    const int tid = threadIdx.x;
    const int nrem = N - n0;

    for (int i = tid; i < 8 * D1; i += 128) {
        int r = i >> 8, k = i & 255;
        xs[r][k] = (r < nrem) ? hmid[(size_t)(n0 + r) * D1 + k] : 0.f;
    }
    __syncthreads();

    float acc[8] = {0.f,0.f,0.f,0.f,0.f,0.f,0.f,0.f};
    for (int k = 0; k < D1; ++k) {
        float wk = W2[k * D2 + tid];
        #pragma unroll
        for (int r = 0; r < 8; ++r) acc[r] += xs[r][k] * wk;
    }

    #pragma unroll
    for (int r = 0; r < 8; ++r)
        if (r < nrem) h2[(size_t)(n0 + r) * D2 + tid] = acc[r];

    const float as_w = att_s[tid];
    const float ad_w = att_d[tid];
    const int lane = tid & 63, head = tid >> 6;  // 2 waves = 2 heads
    #pragma unroll
    for (int r = 0; r < 8; ++r) {
        float ps = acc[r] * as_w;
        float pd = acc[r] * ad_w;
        for (int off = 32; off > 0; off >>= 1) {
            ps += __shfl_down(ps, off);
            pd += __shfl_down(pd, off);
        }
        if (lane == 0 && r < nrem) {
            al_s[(size_t)(n0 + r) * H2 + head] = ps;
            al_d[(size_t)(n0 + r) * H2 + head] = pd;
        }
    }
}

// ---------------- Edge pass: single-pass unnormalized softmax-aggregate ----------------
// 64 lanes per edge; lane = channel. w = exp(leaky_relu(logit));
// acc[dst,h,c] += w*h[src,h,c]; denom[dst,h] += w. Shift-invariance of softmax
// makes the max-subtraction pass unnecessary (logits are O(10), no overflow).
template<int H>
__global__ __launch_bounds__(256) void edge_pass(
    const int* __restrict__ ei,        // [2,E] as int32 or int64 (see flag)
    const int* __restrict__ i64flag,
    int E, int nTot,                   // nTot = E + N (self loops appended)
    const float* __restrict__ hfeat,   // [N, H*64]
    const float* __restrict__ al_s,    // [N,H]
    const float* __restrict__ al_d,    // [N,H]
    float* __restrict__ acc,           // [N, H*64]
    float* __restrict__ denom)         // [N,H]
{
    const int t = blockIdx.x * 256 + threadIdx.x;
    const int e = t >> 6;
    const int lane = t & 63;
    if (e >= nTot) return;

    int src, dst;
    if (e < E) {
        if (*i64flag) { src = ei[2 * (size_t)e]; dst = ei[2 * ((size_t)E + e)]; }
        else          { src = ei[e];             dst = ei[E + e]; }
    } else {
        src = dst = e - E;
    }

    const int D = H * 64;
    float w[H];
    #pragma unroll
    for (int h = 0; h < H; ++h) {
        float v = al_s[(size_t)src * H + h] + al_d[(size_t)dst * H + h];
        v = v > 0.f ? v : LRELU * v;
        w[h] = __expf(v);
    }
    #pragma unroll
    for (int h = 0; h < H; ++h) {
        float hv = hfeat[(size_t)src * D + h * 64 + lane];
        atomicAdd(&acc[(size_t)dst * D + h * 64 + lane], w[h] * hv);
    }
    if (lane < H) atomicAdd(&denom[(size_t)dst * H + lane], w[lane]);
}

// ---------------- Node pass 1: normalize + bias + LayerNorm + ELU ----------------
__global__ __launch_bounds__(256) void node_pass1(
    const float* acc, const float* __restrict__ denom,
    const float* __restrict__ b1,
    const float* __restrict__ ln_w,
    const float* __restrict__ ln_b,
    float* hmid)
{
    const int n = blockIdx.x, t = threadIdx.x;
    float v = acc[(size_t)n * D1 + t] / denom[(size_t)n * H1 + (t >> 6)] + b1[t];

    float s = v, s2 = v * v;
    for (int off = 32; off > 0; off >>= 1) {
        s  += __shfl_down(s,  off);
        s2 += __shfl_down(s2, off);
    }
    __shared__ float ls[4], ls2[4];
    const int lane = t & 63, w = t >> 6;
    if (lane == 0) { ls[w] = s; ls2[w] = s2; }
    __syncthreads();
    const float mu  = (ls[0] + ls[1] + ls[2] + ls[3]) * (1.f / 256.f);
    const float ex2 = (ls2[0] + ls2[1] + ls2[2] + ls2[3]) * (1.f / 256.f);
    const float var = ex2 - mu * mu;
    float y = (v - mu) * rsqrtf(var + LN_EPS) * ln_w[t] + ln_b[t];
    y = y > 0.f ? y : (__expf(y) - 1.f);   // ELU
    hmid[(size_t)n * D1 + t] = y;
}

// ---------------- Node pass 2: normalize, mean over heads, + b2 ----------------
__global__ __launch_bounds__(64) void node_pass2(
    const float* __restrict__ acc, const float* __restrict__ denom,
    const float* __restrict__ b2,
    float* __restrict__ out)
{
    const int n = blockIdx.x, t = threadIdx.x;
    const float v0 = acc[(size_t)n * D2 + t]      / denom[(size_t)n * 2 + 0];
    const float v1 = acc[(size_t)n * D2 + 64 + t] / denom[(size_t)n * 2 + 1];
    out[(size_t)n * OUT_DIM + t] = 0.5f * (v0 + v1) + b2[t];
}

extern "C" void kernel_launch(void* const* d_in, const int* in_sizes, int n_in,
                              void* d_out, int out_size, void* d_ws, size_t ws_size,
                              hipStream_t stream)
{
    const float* x   = (const float*)d_in[0];
    const int*   ei  = (const int*)d_in[1];
    const float* W1  = (const float*)d_in[2];
    const float* as1 = (const float*)d_in[3];
    const float* ad1 = (const float*)d_in[4];
    const float* b1  = (const float*)d_in[5];
    const float* lnw = (const float*)d_in[6];
    const float* lnb = (const float*)d_in[7];
    const float* W2  = (const float*)d_in[8];
    const float* as2 = (const float*)d_in[9];
    const float* ad2 = (const float*)d_in[10];
    const float* b2  = (const float*)d_in[11];

    const int N    = in_sizes[0] / IN_DIM;   // 50000
    const int E    = in_sizes[1] / 2;        // 800000
    const int nTot = E + N;                  // edges + self loops

    // workspace layout (with reuse):
    //   bufA [N*256 f32]: h1  -> later h2 (first half) + acc2 (second half)
    //   bufB [N*256 f32]: acc1 -> hmid (elementwise alias)
    //   small: al/denoms + i64 flag
    char* ws = (char*)d_ws;
    const size_t szBig = (size_t)N * D1 * sizeof(float);
    float* h1     = (float*)(ws);
    float* accB   = (float*)(ws + szBig);
    float* smallp = (float*)(ws + 2 * szBig);
    float* al_s1  = smallp;
    float* al_d1  = al_s1 + (size_t)N * H1;
    float* denom1 = al_d1 + (size_t)N * H1;
    float* al_s2  = denom1 + (size_t)N * H1;
    float* al_d2  = al_s2 + (size_t)N * H2;
    float* denom2 = al_d2 + (size_t)N * H2;
    int*   i64f   = (int*)(denom2 + (size_t)N * H2);
    float* h2     = (float*)(ws);                       // reuse bufA
    float* acc2   = (float*)(ws) + (size_t)N * D2;      // bufA second half

    hipMemsetAsync(accB,   0, szBig,                          stream);
    hipMemsetAsync(denom1, 0, (size_t)N * H1 * sizeof(float), stream);
    hipMemsetAsync(denom2, 0, (size_t)N * H2 * sizeof(float), stream);

    const int nodeBlocks8 = (N + 7) / 8;
    const int edgeBlocks  = (nTot + 3) / 4;   // 4 edges/block, 64 lanes/edge

    detect_i64_kernel<<<1, 1, 0, stream>>>(ei, i64f);
    gemm1_kernel<<<nodeBlocks8, 256, 0, stream>>>(x, W1, as1, ad1, h1, al_s1, al_d1, N);
    edge_pass<H1><<<edgeBlocks, 256, 0, stream>>>(ei, i64f, E, nTot, h1, al_s1, al_d1, accB, denom1);
    node_pass1<<<N, 256, 0, stream>>>(accB, denom1, b1, lnw, lnb, accB);
    hipMemsetAsync(acc2, 0, (size_t)N * D2 * sizeof(float), stream);
    gemm2_kernel<<<nodeBlocks8, 128, 0, stream>>>(accB, W2, as2, ad2, h2, al_s2, al_d2, N);
    edge_pass<H2><<<edgeBlocks, 256, 0, stream>>>(ei, i64f, E, nTot, h2, al_s2, al_d2, acc2, denom2);
    node_pass2<<<N, 64, 0, stream>>>(acc2, denom2, b2, (float*)d_out);
}

// Round 3
// 656.067 us; speedup vs baseline: 2.1716x; 2.1716x over previous
//
#include <hip/hip_runtime.h>
#include <hip/hip_bf16.h>
#include <math.h>

#define IN_DIM  128
#define HID     64
#define H1      4
#define H2      2
#define OUT_DIM 64
#define D1      256   // H1*HID
#define D2      128   // H2*OUT_DIM
#define LRELU   0.2f
#define LN_EPS  1e-5f

// ---------------- edge_index dtype probe ----------------
// int64 edge_index: odd int32 words of the src row are zero high-halves.
__global__ void detect_i64_kernel(const int* __restrict__ ei, int* __restrict__ flag)
{
    int any_odd_nonzero = 0;
    #pragma unroll
    for (int k = 1; k < 16; k += 2) any_odd_nonzero |= (ei[k] != 0);
    *flag = any_odd_nonzero ? 0 : 1;
}

// ---------------- CSR build: histogram, 3-kernel scan, fill ----------------
__global__ __launch_bounds__(256) void hist_kernel(
    const int* __restrict__ ei, const int* __restrict__ i64f, int E,
    int* __restrict__ deg)
{
    int e = blockIdx.x * 256 + threadIdx.x;
    if (e >= E) return;
    int dst = (*i64f) ? ei[2 * ((size_t)E + e)] : ei[E + e];
    atomicAdd(&deg[dst], 1);
}

__global__ __launch_bounds__(256) void scan_partial(
    const int* __restrict__ deg, int N, int* __restrict__ bsum)
{
    __shared__ int s[256];
    int i = blockIdx.x * 256 + threadIdx.x;
    s[threadIdx.x] = (i < N) ? deg[i] : 0;
    __syncthreads();
    for (int st = 128; st > 0; st >>= 1) {
        if (threadIdx.x < st) s[threadIdx.x] += s[threadIdx.x + st];
        __syncthreads();
    }
    if (threadIdx.x == 0) bsum[blockIdx.x] = s[0];
}

// single block; B <= 256. In-place exclusive scan of bsum; writes total to *totalp.
__global__ __launch_bounds__(256) void scan_top(
    int* __restrict__ bsum, int B, int* __restrict__ totalp)
{
    __shared__ int s[256];
    int v = (threadIdx.x < B) ? bsum[threadIdx.x] : 0;
    s[threadIdx.x] = v;
    __syncthreads();
    for (int st = 1; st < 256; st <<= 1) {
        int t = (threadIdx.x >= st) ? s[threadIdx.x - st] : 0;
        __syncthreads();
        s[threadIdx.x] += t;
        __syncthreads();
    }
    if (threadIdx.x < B) bsum[threadIdx.x] = s[threadIdx.x] - v;
    if (threadIdx.x == 255) *totalp = s[255];
}

__global__ __launch_bounds__(256) void scan_final(
    const int* __restrict__ deg, const int* __restrict__ bsum, int N,
    int* __restrict__ rowptr, int* __restrict__ cursor)
{
    __shared__ int s[256];
    int i = blockIdx.x * 256 + threadIdx.x;
    int v = (i < N) ? deg[i] : 0;
    s[threadIdx.x] = v;
    __syncthreads();
    for (int st = 1; st < 256; st <<= 1) {
        int t = (threadIdx.x >= st) ? s[threadIdx.x - st] : 0;
        __syncthreads();
        s[threadIdx.x] += t;
        __syncthreads();
    }
    int excl = s[threadIdx.x] - v + bsum[blockIdx.x];
    if (i < N) { rowptr[i] = excl; cursor[i] = excl; }
}

__global__ __launch_bounds__(256) void fill_kernel(
    const int* __restrict__ ei, const int* __restrict__ i64f, int E,
    int* __restrict__ cursor, int* __restrict__ csr_src)
{
    int e = blockIdx.x * 256 + threadIdx.x;
    if (e >= E) return;
    int src, dst;
    if (*i64f) { src = ei[2 * (size_t)e]; dst = ei[2 * ((size_t)E + e)]; }
    else       { src = ei[e];             dst = ei[E + e]; }
    int pos = atomicAdd(&cursor[dst], 1);
    csr_src[pos] = src;
}

// ---------------- GEMM1: h1 = x @ W1, fused attention logits ----------------
__global__ __launch_bounds__(256) void gemm1_kernel(
    const float* __restrict__ x,      // [N,128]
    const float* __restrict__ W1,     // [128,256]
    const float* __restrict__ att_s,  // [256]
    const float* __restrict__ att_d,  // [256]
    float* __restrict__ h1,           // [N,256]
    float* __restrict__ al_s,         // [N,4]
    float* __restrict__ al_d,         // [N,4]
    int N)
{
    __shared__ float xs[8][IN_DIM];
    const int n0 = blockIdx.x * 8;
    const int tid = threadIdx.x;
    const int nrem = N - n0;

    for (int i = tid; i < 8 * IN_DIM; i += 256) {
        int r = i >> 7, k = i & 127;
        xs[r][k] = (r < nrem) ? x[(size_t)(n0 + r) * IN_DIM + k] : 0.f;
    }
    __syncthreads();

    float acc[8] = {0.f,0.f,0.f,0.f,0.f,0.f,0.f,0.f};
    for (int k = 0; k < IN_DIM; ++k) {
        float wk = W1[k * D1 + tid];
        #pragma unroll
        for (int r = 0; r < 8; ++r) acc[r] += xs[r][k] * wk;
    }

    #pragma unroll
    for (int r = 0; r < 8; ++r)
        if (r < nrem) h1[(size_t)(n0 + r) * D1 + tid] = acc[r];

    const float as_w = att_s[tid];
    const float ad_w = att_d[tid];
    const int lane = tid & 63, head = tid >> 6;
    #pragma unroll
    for (int r = 0; r < 8; ++r) {
        float ps = acc[r] * as_w;
        float pd = acc[r] * ad_w;
        for (int off = 32; off > 0; off >>= 1) {
            ps += __shfl_down(ps, off);
            pd += __shfl_down(pd, off);
        }
        if (lane == 0 && r < nrem) {
            al_s[(size_t)(n0 + r) * H1 + head] = ps;
            al_d[(size_t)(n0 + r) * H1 + head] = pd;
        }
    }
}

// ---------------- GEMM2: h2 = hmid @ W2, fused attention logits ----------------
__global__ __launch_bounds__(128) void gemm2_kernel(
    const float* __restrict__ hmid,   // [N,256]
    const float* __restrict__ W2,     // [256,128]
    const float* __restrict__ att_s,  // [128]
    const float* __restrict__ att_d,  // [128]
    float* __restrict__ h2,           // [N,128]
    float* __restrict__ al_s,         // [N,2]
    float* __restrict__ al_d,         // [N,2]
    int N)
{
    __shared__ float xs[8][D1];
    const int n0 = blockIdx.x * 8;
    const int tid = threadIdx.x;
    const int nrem = N - n0;

    for (int i = tid; i < 8 * D1; i += 128) {
        int r = i >> 8, k = i & 255;
        xs[r][k] = (r < nrem) ? hmid[(size_t)(n0 + r) * D1 + k] : 0.f;
    }
    __syncthreads();

    float acc[8] = {0.f,0.f,0.f,0.f,0.f,0.f,0.f,0.f};
    for (int k = 0; k < D1; ++k) {
        float wk = W2[k * D2 + tid];
        #pragma unroll
        for (int r = 0; r < 8; ++r) acc[r] += xs[r][k] * wk;
    }

    #pragma unroll
    for (int r = 0; r < 8; ++r)
        if (r < nrem) h2[(size_t)(n0 + r) * D2 + tid] = acc[r];

    const float as_w = att_s[tid];
    const float ad_w = att_d[tid];
    const int lane = tid & 63, head = tid >> 6;
    #pragma unroll
    for (int r = 0; r < 8; ++r) {
        float ps = acc[r] * as_w;
        float pd = acc[r] * ad_w;
        for (int off = 32; off > 0; off >>= 1) {
            ps += __shfl_down(ps, off);
            pd += __shfl_down(pd, off);
        }
        if (lane == 0 && r < nrem) {
            al_s[(size_t)(n0 + r) * H2 + head] = ps;
            al_d[(size_t)(n0 + r) * H2 + head] = pd;
        }
    }
}

// ---------------- Layer-1 aggregation (CSR gather) + LN + ELU epilogue ----------------
// One block (256 threads) per dst node; thread = channel (head = t>>6).
// Softmax denominator: every lane of a head's wave computes identical w, so the
// per-thread running sum IS the denominator — no reduction needed.
__global__ __launch_bounds__(256) void agg1_kernel(
    const int* __restrict__ rowptr, const int* __restrict__ csr_src,
    const float* __restrict__ h1,
    const float* __restrict__ al_s, const float* __restrict__ al_d,
    const float* __restrict__ b1,
    const float* __restrict__ ln_w, const float* __restrict__ ln_b,
    float* __restrict__ hmid, int N)
{
    const int n = blockIdx.x;
    const int t = threadIdx.x;
    const int h = t >> 6;
    const float ad = al_d[(size_t)n * H1 + h];

    // self loop
    float v0 = al_s[(size_t)n * H1 + h] + ad;
    v0 = v0 > 0.f ? v0 : LRELU * v0;
    const float wself = __expf(v0);
    float acc = wself * h1[(size_t)n * D1 + t];
    float den = wself;

    const int beg = rowptr[n], end = rowptr[n + 1];
    for (int i = beg; i < end; ++i) {
        int src = csr_src[i];
        float v = al_s[(size_t)src * H1 + h] + ad;
        v = v > 0.f ? v : LRELU * v;
        float w = __expf(v);
        acc += w * h1[(size_t)src * D1 + t];
        den += w;
    }

    float val = acc / den + b1[t];

    // LayerNorm over 256 channels
    float s = val, s2 = val * val;
    for (int off = 32; off > 0; off >>= 1) {
        s  += __shfl_down(s,  off);
        s2 += __shfl_down(s2, off);
    }
    __shared__ float ls[4], ls2[4];
    const int lane = t & 63;
    if (lane == 0) { ls[h] = s; ls2[h] = s2; }
    __syncthreads();
    const float mu  = (ls[0] + ls[1] + ls[2] + ls[3]) * (1.f / 256.f);
    const float ex2 = (ls2[0] + ls2[1] + ls2[2] + ls2[3]) * (1.f / 256.f);
    const float var = ex2 - mu * mu;
    float y = (val - mu) * rsqrtf(var + LN_EPS) * ln_w[t] + ln_b[t];
    y = y > 0.f ? y : (__expf(y) - 1.f);   // ELU
    hmid[(size_t)n * D1 + t] = y;
}

// ---------------- Layer-2 aggregation + head-mean + bias -> out ----------------
__global__ __launch_bounds__(128) void agg2_kernel(
    const int* __restrict__ rowptr, const int* __restrict__ csr_src,
    const float* __restrict__ h2,
    const float* __restrict__ al_s, const float* __restrict__ al_d,
    const float* __restrict__ b2,
    float* __restrict__ out, int N)
{
    const int n = blockIdx.x;
    const int t = threadIdx.x;
    const int h = t >> 6, lane = t & 63;
    const float ad = al_d[(size_t)n * H2 + h];

    float v0 = al_s[(size_t)n * H2 + h] + ad;
    v0 = v0 > 0.f ? v0 : LRELU * v0;
    const float wself = __expf(v0);
    float acc = wself * h2[(size_t)n * D2 + t];
    float den = wself;

    const int beg = rowptr[n], end = rowptr[n + 1];
    for (int i = beg; i < end; ++i) {
        int src = csr_src[i];
        float v = al_s[(size_t)src * H2 + h] + ad;
        v = v > 0.f ? v : LRELU * v;
        float w = __expf(v);
        acc += w * h2[(size_t)src * D2 + t];
        den += w;
    }

    float val = acc / den;
    __shared__ float tmp[64];
    if (h == 1) tmp[lane] = val;
    __syncthreads();
    if (h == 0) out[(size_t)n * OUT_DIM + lane] = 0.5f * (val + tmp[lane]) + b2[lane];
}

extern "C" void kernel_launch(void* const* d_in, const int* in_sizes, int n_in,
                              void* d_out, int out_size, void* d_ws, size_t ws_size,
                              hipStream_t stream)
{
    const float* x   = (const float*)d_in[0];
    const int*   ei  = (const int*)d_in[1];
    const float* W1  = (const float*)d_in[2];
    const float* as1 = (const float*)d_in[3];
    const float* ad1 = (const float*)d_in[4];
    const float* b1  = (const float*)d_in[5];
    const float* lnw = (const float*)d_in[6];
    const float* lnb = (const float*)d_in[7];
    const float* W2  = (const float*)d_in[8];
    const float* as2 = (const float*)d_in[9];
    const float* ad2 = (const float*)d_in[10];
    const float* b2  = (const float*)d_in[11];

    const int N = in_sizes[0] / IN_DIM;   // 50000
    const int E = in_sizes[1] / 2;        // 800000

    // workspace layout:
    //   bufA [N*256 f32]: h1, later h2 in first N*128
    //   bufB [N*256 f32]: hmid
    //   al_s1/al_d1 [N*4], al_s2/al_d2 [N*2]
    //   deg/rowptr/cursor [N+1 ints], csr_src [E ints], bsum [256], i64 flag
    char* ws = (char*)d_ws;
    const size_t szBig = (size_t)N * D1 * sizeof(float);
    float* h1    = (float*)(ws);
    float* hmid  = (float*)(ws + szBig);
    float* al_s1 = (float*)(ws + 2 * szBig);
    float* al_d1 = al_s1 + (size_t)N * H1;
    float* al_s2 = al_d1 + (size_t)N * H1;
    float* al_d2 = al_s2 + (size_t)N * H2;
    int* deg     = (int*)(al_d2 + (size_t)N * H2);
    int* rowptr  = deg + (N + 1);
    int* cursor  = rowptr + (N + 1);
    int* csr_src = cursor + (N + 1);
    int* bsum    = csr_src + E;
    int* i64f    = bsum + 256;
    float* h2    = (float*)(ws);   // reuse bufA after agg1

    hipMemsetAsync(deg, 0, (size_t)(N + 1) * sizeof(int), stream);

    const int edgeBlocks  = (E + 255) / 256;
    const int scanBlocks  = (N + 255) / 256;   // 196 <= 256
    const int nodeBlocks8 = (N + 7) / 8;

    detect_i64_kernel<<<1, 1, 0, stream>>>(ei, i64f);
    hist_kernel<<<edgeBlocks, 256, 0, stream>>>(ei, i64f, E, deg);
    scan_partial<<<scanBlocks, 256, 0, stream>>>(deg, N, bsum);
    scan_top<<<1, 256, 0, stream>>>(bsum, scanBlocks, rowptr + N);
    scan_final<<<scanBlocks, 256, 0, stream>>>(deg, bsum, N, rowptr, cursor);
    fill_kernel<<<edgeBlocks, 256, 0, stream>>>(ei, i64f, E, cursor, csr_src);

    gemm1_kernel<<<nodeBlocks8, 256, 0, stream>>>(x, W1, as1, ad1, h1, al_s1, al_d1, N);
    agg1_kernel<<<N, 256, 0, stream>>>(rowptr, csr_src, h1, al_s1, al_d1,
                                       b1, lnw, lnb, hmid, N);
    gemm2_kernel<<<nodeBlocks8, 128, 0, stream>>>(hmid, W2, as2, ad2, h2, al_s2, al_d2, N);
    agg2_kernel<<<N, 128, 0, stream>>>(rowptr, csr_src, h2, al_s2, al_d2,
                                       b2, (float*)d_out, N);
}

// Round 4
// 451.522 us; speedup vs baseline: 3.1554x; 1.4530x over previous
//
#include <hip/hip_runtime.h>
#include <hip/hip_bf16.h>
#include <math.h>

#define IN_DIM  128
#define HID     64
#define H1      4
#define H2      2
#define OUT_DIM 64
#define D1      256   // H1*HID
#define D2      128   // H2*OUT_DIM
#define LRELU   0.2f
#define LN_EPS  1e-5f

static __device__ __forceinline__ float2 unpack_bf2(unsigned int p)
{
    float2 r;
    r.x = __uint_as_float(p << 16);
    r.y = __uint_as_float(p & 0xffff0000u);
    return r;
}

template<int H>
static __device__ __forceinline__ float edge_w(
    const float* __restrict__ al_s, int src, float ad, int h)
{
    float v = al_s[(size_t)src * H + h] + ad;
    v = v > 0.f ? v : LRELU * v;
    return __expf(v);
}

// ---------------- edge_index dtype probe ----------------
// int64 edge_index: odd int32 words of the src row are zero high-halves.
__global__ void detect_i64_kernel(const int* __restrict__ ei, int* __restrict__ flag)
{
    int any_odd_nonzero = 0;
    #pragma unroll
    for (int k = 1; k < 16; k += 2) any_odd_nonzero |= (ei[k] != 0);
    *flag = any_odd_nonzero ? 0 : 1;
}

// ---------------- CSR build: histogram, 3-kernel scan, fill ----------------
__global__ __launch_bounds__(256) void hist_kernel(
    const int* __restrict__ ei, const int* __restrict__ i64f, int E,
    int* __restrict__ deg)
{
    int e = blockIdx.x * 256 + threadIdx.x;
    if (e >= E) return;
    int dst = (*i64f) ? ei[2 * ((size_t)E + e)] : ei[E + e];
    atomicAdd(&deg[dst], 1);
}

__global__ __launch_bounds__(256) void scan_partial(
    const int* __restrict__ deg, int N, int* __restrict__ bsum)
{
    __shared__ int s[256];
    int i = blockIdx.x * 256 + threadIdx.x;
    s[threadIdx.x] = (i < N) ? deg[i] : 0;
    __syncthreads();
    for (int st = 128; st > 0; st >>= 1) {
        if (threadIdx.x < st) s[threadIdx.x] += s[threadIdx.x + st];
        __syncthreads();
    }
    if (threadIdx.x == 0) bsum[blockIdx.x] = s[0];
}

__global__ __launch_bounds__(256) void scan_top(
    int* __restrict__ bsum, int B, int* __restrict__ totalp)
{
    __shared__ int s[256];
    int v = (threadIdx.x < B) ? bsum[threadIdx.x] : 0;
    s[threadIdx.x] = v;
    __syncthreads();
    for (int st = 1; st < 256; st <<= 1) {
        int t = (threadIdx.x >= st) ? s[threadIdx.x - st] : 0;
        __syncthreads();
        s[threadIdx.x] += t;
        __syncthreads();
    }
    if (threadIdx.x < B) bsum[threadIdx.x] = s[threadIdx.x] - v;
    if (threadIdx.x == 255) *totalp = s[255];
}

__global__ __launch_bounds__(256) void scan_final(
    const int* __restrict__ deg, const int* __restrict__ bsum, int N,
    int* __restrict__ rowptr, int* __restrict__ cursor)
{
    __shared__ int s[256];
    int i = blockIdx.x * 256 + threadIdx.x;
    int v = (i < N) ? deg[i] : 0;
    s[threadIdx.x] = v;
    __syncthreads();
    for (int st = 1; st < 256; st <<= 1) {
        int t = (threadIdx.x >= st) ? s[threadIdx.x - st] : 0;
        __syncthreads();
        s[threadIdx.x] += t;
        __syncthreads();
    }
    int excl = s[threadIdx.x] - v + bsum[blockIdx.x];
    if (i < N) { rowptr[i] = excl; cursor[i] = excl; }
}

__global__ __launch_bounds__(256) void fill_kernel(
    const int* __restrict__ ei, const int* __restrict__ i64f, int E,
    int* __restrict__ cursor, int* __restrict__ csr_src)
{
    int e = blockIdx.x * 256 + threadIdx.x;
    if (e >= E) return;
    int src, dst;
    if (*i64f) { src = ei[2 * (size_t)e]; dst = ei[2 * ((size_t)E + e)]; }
    else       { src = ei[e];             dst = ei[E + e]; }
    int pos = atomicAdd(&cursor[dst], 1);
    csr_src[pos] = src;
}

// ---------------- GEMM1: h1 = x @ W1 (bf16 out), fused attention logits ----------------
__global__ __launch_bounds__(256) void gemm1_kernel(
    const float* __restrict__ x,      // [N,128]
    const float* __restrict__ W1,     // [128,256]
    const float* __restrict__ att_s,  // [256]
    const float* __restrict__ att_d,  // [256]
    __hip_bfloat16* __restrict__ h1b, // [N,256] bf16
    float* __restrict__ al_s,         // [N,4]
    float* __restrict__ al_d,         // [N,4]
    int N)
{
    __shared__ float xs[8][IN_DIM];
    const int n0 = blockIdx.x * 8;
    const int tid = threadIdx.x;
    const int nrem = N - n0;

    for (int i = tid; i < 8 * IN_DIM; i += 256) {
        int r = i >> 7, k = i & 127;
        xs[r][k] = (r < nrem) ? x[(size_t)(n0 + r) * IN_DIM + k] : 0.f;
    }
    __syncthreads();

    float acc[8] = {0.f,0.f,0.f,0.f,0.f,0.f,0.f,0.f};
    for (int k = 0; k < IN_DIM; ++k) {
        float wk = W1[k * D1 + tid];
        #pragma unroll
        for (int r = 0; r < 8; ++r) acc[r] += xs[r][k] * wk;
    }

    #pragma unroll
    for (int r = 0; r < 8; ++r)
        if (r < nrem) h1b[(size_t)(n0 + r) * D1 + tid] = __float2bfloat16(acc[r]);

    const float as_w = att_s[tid];
    const float ad_w = att_d[tid];
    const int lane = tid & 63, head = tid >> 6;
    #pragma unroll
    for (int r = 0; r < 8; ++r) {
        float ps = acc[r] * as_w;
        float pd = acc[r] * ad_w;
        for (int off = 32; off > 0; off >>= 1) {
            ps += __shfl_down(ps, off);
            pd += __shfl_down(pd, off);
        }
        if (lane == 0 && r < nrem) {
            al_s[(size_t)(n0 + r) * H1 + head] = ps;
            al_d[(size_t)(n0 + r) * H1 + head] = pd;
        }
    }
}

// ---------------- GEMM2: h2 = hmid @ W2 (bf16 out), fused attention logits ----------------
__global__ __launch_bounds__(128) void gemm2_kernel(
    const float* __restrict__ hmid,   // [N,256]
    const float* __restrict__ W2,     // [256,128]
    const float* __restrict__ att_s,  // [128]
    const float* __restrict__ att_d,  // [128]
    __hip_bfloat16* __restrict__ h2b, // [N,128] bf16
    float* __restrict__ al_s,         // [N,2]
    float* __restrict__ al_d,         // [N,2]
    int N)
{
    __shared__ float xs[8][D1];
    const int n0 = blockIdx.x * 8;
    const int tid = threadIdx.x;
    const int nrem = N - n0;

    for (int i = tid; i < 8 * D1; i += 128) {
        int r = i >> 8, k = i & 255;
        xs[r][k] = (r < nrem) ? hmid[(size_t)(n0 + r) * D1 + k] : 0.f;
    }
    __syncthreads();

    float acc[8] = {0.f,0.f,0.f,0.f,0.f,0.f,0.f,0.f};
    for (int k = 0; k < D1; ++k) {
        float wk = W2[k * D2 + tid];
        #pragma unroll
        for (int r = 0; r < 8; ++r) acc[r] += xs[r][k] * wk;
    }

    #pragma unroll
    for (int r = 0; r < 8; ++r)
        if (r < nrem) h2b[(size_t)(n0 + r) * D2 + tid] = __float2bfloat16(acc[r]);

    const float as_w = att_s[tid];
    const float ad_w = att_d[tid];
    const int lane = tid & 63, head = tid >> 6;
    #pragma unroll
    for (int r = 0; r < 8; ++r) {
        float ps = acc[r] * as_w;
        float pd = acc[r] * ad_w;
        for (int off = 32; off > 0; off >>= 1) {
            ps += __shfl_down(ps, off);
            pd += __shfl_down(pd, off);
        }
        if (lane == 0 && r < nrem) {
            al_s[(size_t)(n0 + r) * H2 + head] = ps;
            al_d[(size_t)(n0 + r) * H2 + head] = pd;
        }
    }
}

// ---------------- Layer-1 aggregation (bf16 gather, 4x unroll) + LN + ELU ----------------
// 128 threads per dst node; thread t owns channels (2t,2t+1); head = t>>5.
// Per-thread running den is already the softmax denominator (w lane-replicated per head).
__global__ __launch_bounds__(128) void agg1_kernel(
    const int* __restrict__ rowptr, const int* __restrict__ csr_src,
    const unsigned int* __restrict__ h1p,   // [N,128] packed bf16x2
    const float* __restrict__ al_s, const float* __restrict__ al_d,
    const float* __restrict__ b1,
    const float* __restrict__ ln_w, const float* __restrict__ ln_b,
    float* __restrict__ hmid, int N)
{
    const int n = blockIdx.x;
    const int t = threadIdx.x;
    const int h = t >> 5;
    const float ad = al_d[(size_t)n * H1 + h];

    // self loop
    const float ws = edge_w<H1>(al_s, n, ad, h);
    float2 hv = unpack_bf2(h1p[(size_t)n * 128 + t]);
    float ax0 = ws * hv.x, ay0 = ws * hv.y, dn0 = ws;
    float ax1 = 0.f, ay1 = 0.f, dn1 = 0.f;
    float ax2 = 0.f, ay2 = 0.f, dn2 = 0.f;
    float ax3 = 0.f, ay3 = 0.f, dn3 = 0.f;

    const int beg = rowptr[n], end = rowptr[n + 1];
    int i = beg;
    for (; i + 4 <= end; i += 4) {
        int s0 = csr_src[i], s1 = csr_src[i+1], s2 = csr_src[i+2], s3 = csr_src[i+3];
        unsigned int p0 = h1p[(size_t)s0 * 128 + t];
        unsigned int p1 = h1p[(size_t)s1 * 128 + t];
        unsigned int p2 = h1p[(size_t)s2 * 128 + t];
        unsigned int p3 = h1p[(size_t)s3 * 128 + t];
        float w0 = edge_w<H1>(al_s, s0, ad, h);
        float w1 = edge_w<H1>(al_s, s1, ad, h);
        float w2 = edge_w<H1>(al_s, s2, ad, h);
        float w3 = edge_w<H1>(al_s, s3, ad, h);
        float2 v0 = unpack_bf2(p0), v1 = unpack_bf2(p1);
        float2 v2 = unpack_bf2(p2), v3 = unpack_bf2(p3);
        ax0 += w0 * v0.x; ay0 += w0 * v0.y; dn0 += w0;
        ax1 += w1 * v1.x; ay1 += w1 * v1.y; dn1 += w1;
        ax2 += w2 * v2.x; ay2 += w2 * v2.y; dn2 += w2;
        ax3 += w3 * v3.x; ay3 += w3 * v3.y; dn3 += w3;
    }
    for (; i < end; ++i) {
        int s0 = csr_src[i];
        unsigned int p0 = h1p[(size_t)s0 * 128 + t];
        float w0 = edge_w<H1>(al_s, s0, ad, h);
        float2 v0 = unpack_bf2(p0);
        ax0 += w0 * v0.x; ay0 += w0 * v0.y; dn0 += w0;
    }

    const float den = (dn0 + dn1) + (dn2 + dn3);
    const float inv = 1.f / den;
    float2 bb = ((const float2*)b1)[t];
    float vx = ((ax0 + ax1) + (ax2 + ax3)) * inv + bb.x;
    float vy = ((ay0 + ay1) + (ay2 + ay3)) * inv + bb.y;

    // LayerNorm over 256 channels (128 threads x 2)
    float s = vx + vy, s2 = vx * vx + vy * vy;
    for (int off = 32; off > 0; off >>= 1) {
        s  += __shfl_down(s,  off);
        s2 += __shfl_down(s2, off);
    }
    __shared__ float ls[2], ls2[2];
    const int wave = t >> 6, lane = t & 63;
    if (lane == 0) { ls[wave] = s; ls2[wave] = s2; }
    __syncthreads();
    const float mu  = (ls[0] + ls[1]) * (1.f / 256.f);
    const float ex2 = (ls2[0] + ls2[1]) * (1.f / 256.f);
    const float rstd = rsqrtf(ex2 - mu * mu + LN_EPS);
    float2 lw = ((const float2*)ln_w)[t];
    float2 lb = ((const float2*)ln_b)[t];
    float yx = (vx - mu) * rstd * lw.x + lb.x;
    float yy = (vy - mu) * rstd * lw.y + lb.y;
    yx = yx > 0.f ? yx : (__expf(yx) - 1.f);
    yy = yy > 0.f ? yy : (__expf(yy) - 1.f);
    ((float2*)hmid)[(size_t)n * 128 + t] = make_float2(yx, yy);
}

// ---------------- Layer-2 aggregation (bf16 gather, 4x unroll) + head-mean ----------------
// 64 threads per dst node; thread t owns channels (2t,2t+1); head = t>>5.
__global__ __launch_bounds__(64) void agg2_kernel(
    const int* __restrict__ rowptr, const int* __restrict__ csr_src,
    const unsigned int* __restrict__ h2p,   // [N,64] packed bf16x2
    const float* __restrict__ al_s, const float* __restrict__ al_d,
    const float* __restrict__ b2,
    float* __restrict__ out, int N)
{
    const int n = blockIdx.x;
    const int t = threadIdx.x;
    const int h = t >> 5;
    const float ad = al_d[(size_t)n * H2 + h];

    const float ws = edge_w<H2>(al_s, n, ad, h);
    float2 hv = unpack_bf2(h2p[(size_t)n * 64 + t]);
    float ax0 = ws * hv.x, ay0 = ws * hv.y, dn0 = ws;
    float ax1 = 0.f, ay1 = 0.f, dn1 = 0.f;
    float ax2 = 0.f, ay2 = 0.f, dn2 = 0.f;
    float ax3 = 0.f, ay3 = 0.f, dn3 = 0.f;

    const int beg = rowptr[n], end = rowptr[n + 1];
    int i = beg;
    for (; i + 4 <= end; i += 4) {
        int s0 = csr_src[i], s1 = csr_src[i+1], s2 = csr_src[i+2], s3 = csr_src[i+3];
        unsigned int p0 = h2p[(size_t)s0 * 64 + t];
        unsigned int p1 = h2p[(size_t)s1 * 64 + t];
        unsigned int p2 = h2p[(size_t)s2 * 64 + t];
        unsigned int p3 = h2p[(size_t)s3 * 64 + t];
        float w0 = edge_w<H2>(al_s, s0, ad, h);
        float w1 = edge_w<H2>(al_s, s1, ad, h);
        float w2 = edge_w<H2>(al_s, s2, ad, h);
        float w3 = edge_w<H2>(al_s, s3, ad, h);
        float2 v0 = unpack_bf2(p0), v1 = unpack_bf2(p1);
        float2 v2 = unpack_bf2(p2), v3 = unpack_bf2(p3);
        ax0 += w0 * v0.x; ay0 += w0 * v0.y; dn0 += w0;
        ax1 += w1 * v1.x; ay1 += w1 * v1.y; dn1 += w1;
        ax2 += w2 * v2.x; ay2 += w2 * v2.y; dn2 += w2;
        ax3 += w3 * v3.x; ay3 += w3 * v3.y; dn3 += w3;
    }
    for (; i < end; ++i) {
        int s0 = csr_src[i];
        unsigned int p0 = h2p[(size_t)s0 * 64 + t];
        float w0 = edge_w<H2>(al_s, s0, ad, h);
        float2 v0 = unpack_bf2(p0);
        ax0 += w0 * v0.x; ay0 += w0 * v0.y; dn0 += w0;
    }

    const float inv = 1.f / ((dn0 + dn1) + (dn2 + dn3));
    const float vx = ((ax0 + ax1) + (ax2 + ax3)) * inv;
    const float vy = ((ay0 + ay1) + (ay2 + ay3)) * inv;

    __shared__ float sv[128];
    sv[2 * t]     = vx;
    sv[2 * t + 1] = vy;
    __syncthreads();
    out[(size_t)n * OUT_DIM + t] = 0.5f * (sv[t] + sv[64 + t]) + b2[t];
}

extern "C" void kernel_launch(void* const* d_in, const int* in_sizes, int n_in,
                              void* d_out, int out_size, void* d_ws, size_t ws_size,
                              hipStream_t stream)
{
    const float* x   = (const float*)d_in[0];
    const int*   ei  = (const int*)d_in[1];
    const float* W1  = (const float*)d_in[2];
    const float* as1 = (const float*)d_in[3];
    const float* ad1 = (const float*)d_in[4];
    const float* b1  = (const float*)d_in[5];
    const float* lnw = (const float*)d_in[6];
    const float* lnb = (const float*)d_in[7];
    const float* W2  = (const float*)d_in[8];
    const float* as2 = (const float*)d_in[9];
    const float* ad2 = (const float*)d_in[10];
    const float* b2  = (const float*)d_in[11];

    const int N = in_sizes[0] / IN_DIM;   // 50000
    const int E = in_sizes[1] / 2;        // 800000

    // workspace layout:
    //   h1b  [N*256 bf16]  (later h2b [N*128 bf16] reuses it)
    //   hmid [N*256 f32]
    //   al_s1/al_d1 [N*4], al_s2/al_d2 [N*2]
    //   deg/rowptr/cursor [N+1 ints], csr_src [E ints], bsum [256], i64 flag
    char* ws = (char*)d_ws;
    const size_t szH1b = (size_t)N * D1 * sizeof(__hip_bfloat16);
    const size_t szMid = (size_t)N * D1 * sizeof(float);
    __hip_bfloat16* h1b = (__hip_bfloat16*)(ws);
    float* hmid  = (float*)(ws + szH1b);
    float* al_s1 = (float*)(ws + szH1b + szMid);
    float* al_d1 = al_s1 + (size_t)N * H1;
    float* al_s2 = al_d1 + (size_t)N * H1;
    float* al_d2 = al_s2 + (size_t)N * H2;
    int* deg     = (int*)(al_d2 + (size_t)N * H2);
    int* rowptr  = deg + (N + 1);
    int* cursor  = rowptr + (N + 1);
    int* csr_src = cursor + (N + 1);
    int* bsum    = csr_src + E;
    int* i64f    = bsum + 256;
    __hip_bfloat16* h2b = (__hip_bfloat16*)(ws);   // reuse after agg1

    hipMemsetAsync(deg, 0, (size_t)(N + 1) * sizeof(int), stream);

    const int edgeBlocks  = (E + 255) / 256;
    const int scanBlocks  = (N + 255) / 256;   // 196 <= 256
    const int nodeBlocks8 = (N + 7) / 8;

    detect_i64_kernel<<<1, 1, 0, stream>>>(ei, i64f);
    hist_kernel<<<edgeBlocks, 256, 0, stream>>>(ei, i64f, E, deg);
    scan_partial<<<scanBlocks, 256, 0, stream>>>(deg, N, bsum);
    scan_top<<<1, 256, 0, stream>>>(bsum, scanBlocks, rowptr + N);
    scan_final<<<scanBlocks, 256, 0, stream>>>(deg, bsum, N, rowptr, cursor);
    fill_kernel<<<edgeBlocks, 256, 0, stream>>>(ei, i64f, E, cursor, csr_src);

    gemm1_kernel<<<nodeBlocks8, 256, 0, stream>>>(x, W1, as1, ad1, h1b, al_s1, al_d1, N);
    agg1_kernel<<<N, 128, 0, stream>>>(rowptr, csr_src, (const unsigned int*)h1b,
                                       al_s1, al_d1, b1, lnw, lnb, hmid, N);
    gemm2_kernel<<<nodeBlocks8, 128, 0, stream>>>(hmid, W2, as2, ad2, h2b, al_s2, al_d2, N);
    agg2_kernel<<<N, 64, 0, stream>>>(rowptr, csr_src, (const unsigned int*)h2b,
                                      al_s2, al_d2, b2, (float*)d_out, N);
}

// Round 5
// 359.477 us; speedup vs baseline: 3.9633x; 1.2561x over previous
//
#include <hip/hip_runtime.h>
#include <hip/hip_bf16.h>
#include <math.h>

#define IN_DIM  128
#define HID     64
#define H1      4
#define H2      2
#define OUT_DIM 64
#define D1      256   // H1*HID
#define D2      128   // H2*OUT_DIM
#define LRELU   0.2f
#define LN_EPS  1e-5f

using short8 = __attribute__((ext_vector_type(8))) short;
using f32x4  = __attribute__((ext_vector_type(4))) float;

static __device__ __forceinline__ unsigned short f2bf_bits(float f)
{
    __hip_bfloat16 b = __float2bfloat16(f);
    return *reinterpret_cast<unsigned short*>(&b);
}
static __device__ __forceinline__ float bfbits2f(unsigned short u)
{
    return __uint_as_float(((unsigned int)u) << 16);
}
static __device__ __forceinline__ float2 unpack_bf2(unsigned int p)
{
    float2 r;
    r.x = __uint_as_float(p << 16);
    r.y = __uint_as_float(p & 0xffff0000u);
    return r;
}

template<int H>
static __device__ __forceinline__ float edge_w(
    const float* __restrict__ al_s, int src, float ad, int h)
{
    float v = al_s[(size_t)src * H + h] + ad;
    v = v > 0.f ? v : LRELU * v;
    return __expf(v);
}

// ---------------- edge_index dtype probe ----------------
__global__ void detect_i64_kernel(const int* __restrict__ ei, int* __restrict__ flag)
{
    int any_odd_nonzero = 0;
    #pragma unroll
    for (int k = 1; k < 16; k += 2) any_odd_nonzero |= (ei[k] != 0);
    *flag = any_odd_nonzero ? 0 : 1;
}

// ---------------- CSR build ----------------
__global__ __launch_bounds__(256) void hist_kernel(
    const int* __restrict__ ei, const int* __restrict__ i64f, int E,
    int* __restrict__ deg)
{
    int e = blockIdx.x * 256 + threadIdx.x;
    if (e >= E) return;
    int dst = (*i64f) ? ei[2 * ((size_t)E + e)] : ei[E + e];
    atomicAdd(&deg[dst], 1);
}

__global__ __launch_bounds__(256) void scan_partial(
    const int* __restrict__ deg, int N, int* __restrict__ bsum)
{
    __shared__ int s[256];
    int i = blockIdx.x * 256 + threadIdx.x;
    s[threadIdx.x] = (i < N) ? deg[i] : 0;
    __syncthreads();
    for (int st = 128; st > 0; st >>= 1) {
        if (threadIdx.x < st) s[threadIdx.x] += s[threadIdx.x + st];
        __syncthreads();
    }
    if (threadIdx.x == 0) bsum[blockIdx.x] = s[0];
}

__global__ __launch_bounds__(256) void scan_top(
    int* __restrict__ bsum, int B, int* __restrict__ totalp)
{
    __shared__ int s[256];
    int v = (threadIdx.x < B) ? bsum[threadIdx.x] : 0;
    s[threadIdx.x] = v;
    __syncthreads();
    for (int st = 1; st < 256; st <<= 1) {
        int t = (threadIdx.x >= st) ? s[threadIdx.x - st] : 0;
        __syncthreads();
        s[threadIdx.x] += t;
        __syncthreads();
    }
    if (threadIdx.x < B) bsum[threadIdx.x] = s[threadIdx.x] - v;
    if (threadIdx.x == 255) *totalp = s[255];
}

__global__ __launch_bounds__(256) void scan_final(
    const int* __restrict__ deg, const int* __restrict__ bsum, int N,
    int* __restrict__ rowptr, int* __restrict__ cursor)
{
    __shared__ int s[256];
    int i = blockIdx.x * 256 + threadIdx.x;
    int v = (i < N) ? deg[i] : 0;
    s[threadIdx.x] = v;
    __syncthreads();
    for (int st = 1; st < 256; st <<= 1) {
        int t = (threadIdx.x >= st) ? s[threadIdx.x - st] : 0;
        __syncthreads();
        s[threadIdx.x] += t;
        __syncthreads();
    }
    int excl = s[threadIdx.x] - v + bsum[blockIdx.x];
    if (i < N) { rowptr[i] = excl; cursor[i] = excl; }
}

__global__ __launch_bounds__(256) void fill_kernel(
    const int* __restrict__ ei, const int* __restrict__ i64f, int E,
    int* __restrict__ cursor, int* __restrict__ csr_src)
{
    int e = blockIdx.x * 256 + threadIdx.x;
    if (e >= E) return;
    int src, dst;
    if (*i64f) { src = ei[2 * (size_t)e]; dst = ei[2 * ((size_t)E + e)]; }
    else       { src = ei[e];             dst = ei[E + e]; }
    int pos = atomicAdd(&cursor[dst], 1);
    csr_src[pos] = src;
}

// ---------------- weight pre-pack into B-fragment order ----------------
// Fragment element (t=kstep, s=stripe, lane l, j) = B[t*32+(l>>4)*8+j][s*16+(l&15)]
// stored at flat ((t*S + s)*64 + l)*8 + j  -> wave loads are contiguous short8.
__global__ __launch_bounds__(256) void conv_w1(
    const float* __restrict__ W1, unsigned short* __restrict__ Wp)
{
    int tid = blockIdx.x * 256 + threadIdx.x;           // 32768 = 4*16*64*8
    if (tid >= 4 * 16 * 64 * 8) return;
    int j = tid & 7, l = (tid >> 3) & 63, rest = tid >> 9;
    int s = rest & 15, t = rest >> 4;
    int k = t * 32 + (l >> 4) * 8 + j, col = s * 16 + (l & 15);
    Wp[tid] = f2bf_bits(W1[k * D1 + col]);
}

__global__ __launch_bounds__(256) void conv_w2(
    const float* __restrict__ W2, unsigned short* __restrict__ Wp)
{
    int tid = blockIdx.x * 256 + threadIdx.x;           // 32768 = 8*8*64*8
    if (tid >= 8 * 8 * 64 * 8) return;
    int j = tid & 7, l = (tid >> 3) & 63, rest = tid >> 9;
    int s = rest & 7, t = rest >> 3;
    int k = t * 32 + (l >> 4) * 8 + j, col = s * 16 + (l & 15);
    Wp[tid] = f2bf_bits(W2[k * D2 + col]);
}

// ---------------- MFMA GEMM1: h1b[N,256] = bf16(x[N,128]) @ W1 ----------------
// One block = one 16-row tile x all 256 cols. 4 waves; wave w covers cols [w*64, w*64+64).
__global__ __launch_bounds__(256) void gemm1_mfma(
    const float* __restrict__ x, const unsigned short* __restrict__ Wp,
    unsigned short* __restrict__ h1b, int N)
{
    __shared__ __align__(16) unsigned short As[16 * 136];  // K=128 pad->136 (2-way only)
    const int tid = threadIdx.x;
    const int n0 = blockIdx.x * 16;
    const int l = tid & 63, w = tid >> 6;

    #pragma unroll
    for (int it = 0; it < 2; ++it) {
        int ch = tid + it * 256;            // 512 chunks of 4 floats
        int r = ch >> 5, c4 = (ch & 31) * 4;
        int row = n0 + r;
        float4 v = (row < N) ? ((const float4*)x)[(size_t)row * 32 + (c4 >> 2)]
                             : make_float4(0.f, 0.f, 0.f, 0.f);
        ushort4 pk = make_ushort4(f2bf_bits(v.x), f2bf_bits(v.y),
                                  f2bf_bits(v.z), f2bf_bits(v.w));
        *(ushort4*)&As[r * 136 + c4] = pk;
    }

    short8 bfr[4][4];
    #pragma unroll
    for (int t = 0; t < 4; ++t)
        #pragma unroll
        for (int p = 0; p < 4; ++p)
            bfr[t][p] = ((const short8*)Wp)[(t * 16 + (w * 4 + p)) * 64 + l];

    __syncthreads();

    f32x4 acc[4] = {{0.f,0.f,0.f,0.f},{0.f,0.f,0.f,0.f},
                    {0.f,0.f,0.f,0.f},{0.f,0.f,0.f,0.f}};
    #pragma unroll
    for (int t = 0; t < 4; ++t) {
        short8 a = *(const short8*)&As[(l & 15) * 136 + t * 32 + (l >> 4) * 8];
        #pragma unroll
        for (int p = 0; p < 4; ++p)
            acc[p] = __builtin_amdgcn_mfma_f32_16x16x32_bf16(a, bfr[t][p], acc[p], 0, 0, 0);
    }

    const int colbase = w * 64 + (l & 15);
    const int rowbase = n0 + (l >> 4) * 4;
    #pragma unroll
    for (int p = 0; p < 4; ++p) {
        int col = colbase + p * 16;
        #pragma unroll
        for (int r = 0; r < 4; ++r) {
            int row = rowbase + r;
            if (row < N) h1b[(size_t)row * D1 + col] = f2bf_bits(acc[p][r]);
        }
    }
}

// ---------------- MFMA GEMM2: h2b[N,128] = hmidb[N,256] @ W2 ----------------
// wave w covers cols [w*32, w*32+32) (2 stripes), K=256 -> 8 ksteps.
__global__ __launch_bounds__(256) void gemm2_mfma(
    const unsigned short* __restrict__ hmidb, const unsigned short* __restrict__ Wp,
    unsigned short* __restrict__ h2b, int N)
{
    __shared__ __align__(16) unsigned short As[16 * 264];  // K=256 pad->264
    const int tid = threadIdx.x;
    const int n0 = blockIdx.x * 16;
    const int l = tid & 63, w = tid >> 6;

    const short8 zero8 = {0,0,0,0,0,0,0,0};
    #pragma unroll
    for (int it = 0; it < 2; ++it) {
        int ch = tid + it * 256;            // 512 chunks of 8 bf16
        int r = ch >> 5, c8 = (ch & 31) * 8;
        int row = n0 + r;
        short8 v = (row < N) ? ((const short8*)hmidb)[(size_t)row * 32 + (ch & 31)] : zero8;
        *(short8*)&As[r * 264 + c8] = v;
    }

    short8 bfr[8][2];
    #pragma unroll
    for (int t = 0; t < 8; ++t)
        #pragma unroll
        for (int q = 0; q < 2; ++q)
            bfr[t][q] = ((const short8*)Wp)[(t * 8 + (w * 2 + q)) * 64 + l];

    __syncthreads();

    f32x4 acc[2] = {{0.f,0.f,0.f,0.f},{0.f,0.f,0.f,0.f}};
    #pragma unroll
    for (int t = 0; t < 8; ++t) {
        short8 a = *(const short8*)&As[(l & 15) * 264 + t * 32 + (l >> 4) * 8];
        #pragma unroll
        for (int q = 0; q < 2; ++q)
            acc[q] = __builtin_amdgcn_mfma_f32_16x16x32_bf16(a, bfr[t][q], acc[q], 0, 0, 0);
    }

    const int colbase = w * 32 + (l & 15);
    const int rowbase = n0 + (l >> 4) * 4;
    #pragma unroll
    for (int q = 0; q < 2; ++q) {
        int col = colbase + q * 16;
        #pragma unroll
        for (int r = 0; r < 4; ++r) {
            int row = rowbase + r;
            if (row < N) h2b[(size_t)row * D2 + col] = f2bf_bits(acc[q][r]);
        }
    }
}

// ---------------- attention logits from bf16 h: shuffle-reduce ----------------
template<int H>
__global__ __launch_bounds__(H * 64) void logits_kernel(
    const unsigned short* __restrict__ hb,
    const float* __restrict__ att_s, const float* __restrict__ att_d,
    float* __restrict__ al_s, float* __restrict__ al_d)
{
    const int n = blockIdx.x, t = threadIdx.x;
    float v = bfbits2f(hb[(size_t)n * (H * 64) + t]);
    float ps = v * att_s[t];
    float pd = v * att_d[t];
    for (int off = 32; off > 0; off >>= 1) {
        ps += __shfl_down(ps, off);
        pd += __shfl_down(pd, off);
    }
    if ((t & 63) == 0) {
        al_s[(size_t)n * H + (t >> 6)] = ps;
        al_d[(size_t)n * H + (t >> 6)] = pd;
    }
}

// ---------------- Layer-1 aggregation (bf16 gather, 4x unroll) + LN + ELU ----------------
__global__ __launch_bounds__(128) void agg1_kernel(
    const int* __restrict__ rowptr, const int* __restrict__ csr_src,
    const unsigned int* __restrict__ h1p,   // [N,128] packed bf16x2
    const float* __restrict__ al_s, const float* __restrict__ al_d,
    const float* __restrict__ b1,
    const float* __restrict__ ln_w, const float* __restrict__ ln_b,
    unsigned int* __restrict__ hmidp, int N)  // [N,128] packed bf16x2 out
{
    const int n = blockIdx.x;
    const int t = threadIdx.x;
    const int h = t >> 5;
    const float ad = al_d[(size_t)n * H1 + h];

    const float ws = edge_w<H1>(al_s, n, ad, h);
    float2 hv = unpack_bf2(h1p[(size_t)n * 128 + t]);
    float ax0 = ws * hv.x, ay0 = ws * hv.y, dn0 = ws;
    float ax1 = 0.f, ay1 = 0.f, dn1 = 0.f;
    float ax2 = 0.f, ay2 = 0.f, dn2 = 0.f;
    float ax3 = 0.f, ay3 = 0.f, dn3 = 0.f;

    const int beg = rowptr[n], end = rowptr[n + 1];
    int i = beg;
    for (; i + 4 <= end; i += 4) {
        int s0 = csr_src[i], s1 = csr_src[i+1], s2 = csr_src[i+2], s3 = csr_src[i+3];
        unsigned int p0 = h1p[(size_t)s0 * 128 + t];
        unsigned int p1 = h1p[(size_t)s1 * 128 + t];
        unsigned int p2 = h1p[(size_t)s2 * 128 + t];
        unsigned int p3 = h1p[(size_t)s3 * 128 + t];
        float w0 = edge_w<H1>(al_s, s0, ad, h);
        float w1 = edge_w<H1>(al_s, s1, ad, h);
        float w2 = edge_w<H1>(al_s, s2, ad, h);
        float w3 = edge_w<H1>(al_s, s3, ad, h);
        float2 v0 = unpack_bf2(p0), v1 = unpack_bf2(p1);
        float2 v2 = unpack_bf2(p2), v3 = unpack_bf2(p3);
        ax0 += w0 * v0.x; ay0 += w0 * v0.y; dn0 += w0;
        ax1 += w1 * v1.x; ay1 += w1 * v1.y; dn1 += w1;
        ax2 += w2 * v2.x; ay2 += w2 * v2.y; dn2 += w2;
        ax3 += w3 * v3.x; ay3 += w3 * v3.y; dn3 += w3;
    }
    for (; i < end; ++i) {
        int s0 = csr_src[i];
        unsigned int p0 = h1p[(size_t)s0 * 128 + t];
        float w0 = edge_w<H1>(al_s, s0, ad, h);
        float2 v0 = unpack_bf2(p0);
        ax0 += w0 * v0.x; ay0 += w0 * v0.y; dn0 += w0;
    }

    const float inv = 1.f / ((dn0 + dn1) + (dn2 + dn3));
    float2 bb = ((const float2*)b1)[t];
    float vx = ((ax0 + ax1) + (ax2 + ax3)) * inv + bb.x;
    float vy = ((ay0 + ay1) + (ay2 + ay3)) * inv + bb.y;

    float s = vx + vy, s2 = vx * vx + vy * vy;
    for (int off = 32; off > 0; off >>= 1) {
        s  += __shfl_down(s,  off);
        s2 += __shfl_down(s2, off);
    }
    __shared__ float ls[2], ls2[2];
    const int wave = t >> 6, lane = t & 63;
    if (lane == 0) { ls[wave] = s; ls2[wave] = s2; }
    __syncthreads();
    const float mu  = (ls[0] + ls[1]) * (1.f / 256.f);
    const float ex2 = (ls2[0] + ls2[1]) * (1.f / 256.f);
    const float rstd = rsqrtf(ex2 - mu * mu + LN_EPS);
    float2 lw = ((const float2*)ln_w)[t];
    float2 lb = ((const float2*)ln_b)[t];
    float yx = (vx - mu) * rstd * lw.x + lb.x;
    float yy = (vy - mu) * rstd * lw.y + lb.y;
    yx = yx > 0.f ? yx : (__expf(yx) - 1.f);
    yy = yy > 0.f ? yy : (__expf(yy) - 1.f);
    hmidp[(size_t)n * 128 + t] =
        (unsigned int)f2bf_bits(yx) | ((unsigned int)f2bf_bits(yy) << 16);
}

// ---------------- Layer-2 aggregation (bf16 gather, 4x unroll) + head-mean ----------------
__global__ __launch_bounds__(64) void agg2_kernel(
    const int* __restrict__ rowptr, const int* __restrict__ csr_src,
    const unsigned int* __restrict__ h2p,   // [N,64] packed bf16x2
    const float* __restrict__ al_s, const float* __restrict__ al_d,
    const float* __restrict__ b2,
    float* __restrict__ out, int N)
{
    const int n = blockIdx.x;
    const int t = threadIdx.x;
    const int h = t >> 5;
    const float ad = al_d[(size_t)n * H2 + h];

    const float ws = edge_w<H2>(al_s, n, ad, h);
    float2 hv = unpack_bf2(h2p[(size_t)n * 64 + t]);
    float ax0 = ws * hv.x, ay0 = ws * hv.y, dn0 = ws;
    float ax1 = 0.f, ay1 = 0.f, dn1 = 0.f;
    float ax2 = 0.f, ay2 = 0.f, dn2 = 0.f;
    float ax3 = 0.f, ay3 = 0.f, dn3 = 0.f;

    const int beg = rowptr[n], end = rowptr[n + 1];
    int i = beg;
    for (; i + 4 <= end; i += 4) {
        int s0 = csr_src[i], s1 = csr_src[i+1], s2 = csr_src[i+2], s3 = csr_src[i+3];
        unsigned int p0 = h2p[(size_t)s0 * 64 + t];
        unsigned int p1 = h2p[(size_t)s1 * 64 + t];
        unsigned int p2 = h2p[(size_t)s2 * 64 + t];
        unsigned int p3 = h2p[(size_t)s3 * 64 + t];
        float w0 = edge_w<H2>(al_s, s0, ad, h);
        float w1 = edge_w<H2>(al_s, s1, ad, h);
        float w2 = edge_w<H2>(al_s, s2, ad, h);
        float w3 = edge_w<H2>(al_s, s3, ad, h);
        float2 v0 = unpack_bf2(p0), v1 = unpack_bf2(p1);
        float2 v2 = unpack_bf2(p2), v3 = unpack_bf2(p3);
        ax0 += w0 * v0.x; ay0 += w0 * v0.y; dn0 += w0;
        ax1 += w1 * v1.x; ay1 += w1 * v1.y; dn1 += w1;
        ax2 += w2 * v2.x; ay2 += w2 * v2.y; dn2 += w2;
        ax3 += w3 * v3.x; ay3 += w3 * v3.y; dn3 += w3;
    }
    for (; i < end; ++i) {
        int s0 = csr_src[i];
        unsigned int p0 = h2p[(size_t)s0 * 64 + t];
        float w0 = edge_w<H2>(al_s, s0, ad, h);
        float2 v0 = unpack_bf2(p0);
        ax0 += w0 * v0.x; ay0 += w0 * v0.y; dn0 += w0;
    }

    const float inv = 1.f / ((dn0 + dn1) + (dn2 + dn3));
    const float vx = ((ax0 + ax1) + (ax2 + ax3)) * inv;
    const float vy = ((ay0 + ay1) + (ay2 + ay3)) * inv;

    __shared__ float sv[128];
    sv[2 * t]     = vx;
    sv[2 * t + 1] = vy;
    __syncthreads();
    out[(size_t)n * OUT_DIM + t] = 0.5f * (sv[t] + sv[64 + t]) + b2[t];
}

extern "C" void kernel_launch(void* const* d_in, const int* in_sizes, int n_in,
                              void* d_out, int out_size, void* d_ws, size_t ws_size,
                              hipStream_t stream)
{
    const float* x   = (const float*)d_in[0];
    const int*   ei  = (const int*)d_in[1];
    const float* W1  = (const float*)d_in[2];
    const float* as1 = (const float*)d_in[3];
    const float* ad1 = (const float*)d_in[4];
    const float* b1  = (const float*)d_in[5];
    const float* lnw = (const float*)d_in[6];
    const float* lnb = (const float*)d_in[7];
    const float* W2  = (const float*)d_in[8];
    const float* as2 = (const float*)d_in[9];
    const float* ad2 = (const float*)d_in[10];
    const float* b2  = (const float*)d_in[11];

    const int N = in_sizes[0] / IN_DIM;   // 50000
    const int E = in_sizes[1] / 2;        // 800000

    // workspace layout:
    //   h1b   [N*256 bf16]  (reused as h2b [N*128 bf16] after agg1)
    //   hmidb [N*256 bf16]
    //   Wp1 [32768 us], Wp2 [32768 us]
    //   al_s1/al_d1 [N*4 f32], al_s2/al_d2 [N*2 f32]
    //   deg/rowptr/cursor [N+1 ints], csr_src [E], bsum [256], i64 flag
    char* ws = (char*)d_ws;
    const size_t szH1b = (size_t)N * D1 * sizeof(unsigned short);
    unsigned short* h1b   = (unsigned short*)(ws);
    unsigned short* hmidb = (unsigned short*)(ws + szH1b);
    unsigned short* Wp1   = (unsigned short*)(ws + 2 * szH1b);
    unsigned short* Wp2   = Wp1 + 32768;
    float* al_s1 = (float*)(Wp2 + 32768);
    float* al_d1 = al_s1 + (size_t)N * H1;
    float* al_s2 = al_d1 + (size_t)N * H1;
    float* al_d2 = al_s2 + (size_t)N * H2;
    int* deg     = (int*)(al_d2 + (size_t)N * H2);
    int* rowptr  = deg + (N + 1);
    int* cursor  = rowptr + (N + 1);
    int* csr_src = cursor + (N + 1);
    int* bsum    = csr_src + E;
    int* i64f    = bsum + 256;
    unsigned short* h2b = h1b;   // reuse after agg1 consumed h1b

    hipMemsetAsync(deg, 0, (size_t)(N + 1) * sizeof(int), stream);

    const int edgeBlocks = (E + 255) / 256;
    const int scanBlocks = (N + 255) / 256;
    const int tileBlocks = (N + 15) / 16;

    detect_i64_kernel<<<1, 1, 0, stream>>>(ei, i64f);
    conv_w1<<<128, 256, 0, stream>>>(W1, Wp1);
    conv_w2<<<128, 256, 0, stream>>>(W2, Wp2);
    hist_kernel<<<edgeBlocks, 256, 0, stream>>>(ei, i64f, E, deg);
    scan_partial<<<scanBlocks, 256, 0, stream>>>(deg, N, bsum);
    scan_top<<<1, 256, 0, stream>>>(bsum, scanBlocks, rowptr + N);
    scan_final<<<scanBlocks, 256, 0, stream>>>(deg, bsum, N, rowptr, cursor);
    fill_kernel<<<edgeBlocks, 256, 0, stream>>>(ei, i64f, E, cursor, csr_src);

    gemm1_mfma<<<tileBlocks, 256, 0, stream>>>(x, Wp1, h1b, N);
    logits_kernel<H1><<<N, H1 * 64, 0, stream>>>(h1b, as1, ad1, al_s1, al_d1);
    agg1_kernel<<<N, 128, 0, stream>>>(rowptr, csr_src, (const unsigned int*)h1b,
                                       al_s1, al_d1, b1, lnw, lnb,
                                       (unsigned int*)hmidb, N);
    gemm2_mfma<<<tileBlocks, 256, 0, stream>>>(hmidb, Wp2, h2b, N);
    logits_kernel<H2><<<N, H2 * 64, 0, stream>>>(h2b, as2, ad2, al_s2, al_d2);
    agg2_kernel<<<N, 64, 0, stream>>>(rowptr, csr_src, (const unsigned int*)h2b,
                                      al_s2, al_d2, b2, (float*)d_out, N);
}

// Round 6
// 318.236 us; speedup vs baseline: 4.4769x; 1.1296x over previous
//
#include <hip/hip_runtime.h>
#include <hip/hip_bf16.h>
#include <math.h>

#define IN_DIM  128
#define HID     64
#define H1      4
#define H2      2
#define OUT_DIM 64
#define D1      256   // H1*HID
#define D2      128   // H2*OUT_DIM
#define LRELU   0.2f
#define LN_EPS  1e-5f

using short8 = __attribute__((ext_vector_type(8))) short;
using f32x4  = __attribute__((ext_vector_type(4))) float;

static __device__ __forceinline__ unsigned short f2bf_bits(float f)
{
    __hip_bfloat16 b = __float2bfloat16(f);
    return *reinterpret_cast<unsigned short*>(&b);
}
static __device__ __forceinline__ float2 unpack_bf2(unsigned int p)
{
    float2 r;
    r.x = __uint_as_float(p << 16);
    r.y = __uint_as_float(p & 0xffff0000u);
    return r;
}
static __device__ __forceinline__ unsigned int pack_bf2(float x, float y)
{
    return (unsigned int)f2bf_bits(x) | ((unsigned int)f2bf_bits(y) << 16);
}

template<int H>
static __device__ __forceinline__ float edge_w(
    const float* __restrict__ al_s, int src, float ad, int h)
{
    float v = al_s[(size_t)src * H + h] + ad;
    v = v > 0.f ? v : LRELU * v;
    return __expf(v);
}

// inline int64-vs-int32 edge_index probe: int64 data has zero odd words.
static __device__ __forceinline__ int detect_i64(const int* __restrict__ ei)
{
    int any_odd_nonzero = 0;
    #pragma unroll
    for (int k = 1; k < 16; k += 2) any_odd_nonzero |= (ei[k] != 0);
    return any_odd_nonzero ? 0 : 1;
}

// ---------------- CSR build ----------------
__global__ __launch_bounds__(256) void hist_kernel(
    const int* __restrict__ ei, int E, int* __restrict__ deg)
{
    const int i64f = detect_i64(ei);
    int e = blockIdx.x * 256 + threadIdx.x;
    if (e >= E) return;
    int dst = i64f ? ei[2 * ((size_t)E + e)] : ei[E + e];
    atomicAdd(&deg[dst], 1);
}

__global__ __launch_bounds__(256) void scan_partial(
    const int* __restrict__ deg, int N, int* __restrict__ bsum)
{
    __shared__ int s[256];
    int i = blockIdx.x * 256 + threadIdx.x;
    s[threadIdx.x] = (i < N) ? deg[i] : 0;
    __syncthreads();
    for (int st = 128; st > 0; st >>= 1) {
        if (threadIdx.x < st) s[threadIdx.x] += s[threadIdx.x + st];
        __syncthreads();
    }
    if (threadIdx.x == 0) bsum[blockIdx.x] = s[0];
}

__global__ __launch_bounds__(256) void scan_top(
    int* __restrict__ bsum, int B, int* __restrict__ totalp)
{
    __shared__ int s[256];
    int v = (threadIdx.x < B) ? bsum[threadIdx.x] : 0;
    s[threadIdx.x] = v;
    __syncthreads();
    for (int st = 1; st < 256; st <<= 1) {
        int t = (threadIdx.x >= st) ? s[threadIdx.x - st] : 0;
        __syncthreads();
        s[threadIdx.x] += t;
        __syncthreads();
    }
    if (threadIdx.x < B) bsum[threadIdx.x] = s[threadIdx.x] - v;
    if (threadIdx.x == 255) *totalp = s[255];
}

__global__ __launch_bounds__(256) void scan_final(
    const int* __restrict__ deg, const int* __restrict__ bsum, int N,
    int* __restrict__ rowptr, int* __restrict__ cursor)
{
    __shared__ int s[256];
    int i = blockIdx.x * 256 + threadIdx.x;
    int v = (i < N) ? deg[i] : 0;
    s[threadIdx.x] = v;
    __syncthreads();
    for (int st = 1; st < 256; st <<= 1) {
        int t = (threadIdx.x >= st) ? s[threadIdx.x - st] : 0;
        __syncthreads();
        s[threadIdx.x] += t;
        __syncthreads();
    }
    int excl = s[threadIdx.x] - v + bsum[blockIdx.x];
    if (i < N) { rowptr[i] = excl; cursor[i] = excl; }
}

__global__ __launch_bounds__(256) void fill_kernel(
    const int* __restrict__ ei, int E,
    int* __restrict__ cursor, int* __restrict__ csr_src)
{
    const int i64f = detect_i64(ei);
    int e = blockIdx.x * 256 + threadIdx.x;
    if (e >= E) return;
    int src, dst;
    if (i64f) { src = ei[2 * (size_t)e]; dst = ei[2 * ((size_t)E + e)]; }
    else      { src = ei[e];             dst = ei[E + e]; }
    int pos = atomicAdd(&cursor[dst], 1);
    csr_src[pos] = src;
}

// ---------------- weight pre-pack (both layers in one kernel) ----------------
// Fragment element (t=kstep, s=stripe, lane l, j) = B[t*32+(l>>4)*8+j][s*16+(l&15)]
__global__ __launch_bounds__(256) void conv_weights(
    const float* __restrict__ W1, const float* __restrict__ W2,
    unsigned short* __restrict__ Wp1, unsigned short* __restrict__ Wp2)
{
    int tid = blockIdx.x * 256 + threadIdx.x;
    if (tid < 32768) {            // W1: 4 ksteps x 16 stripes
        int j = tid & 7, l = (tid >> 3) & 63, rest = tid >> 9;
        int s = rest & 15, t = rest >> 4;
        int k = t * 32 + (l >> 4) * 8 + j, col = s * 16 + (l & 15);
        Wp1[tid] = f2bf_bits(W1[k * D1 + col]);
    } else {                      // W2: 8 ksteps x 8 stripes
        int id = tid - 32768;
        int j = id & 7, l = (id >> 3) & 63, rest = id >> 9;
        int s = rest & 7, t = rest >> 3;
        int k = t * 32 + (l >> 4) * 8 + j, col = s * 16 + (l & 15);
        Wp2[id] = f2bf_bits(W2[k * D2 + col]);
    }
}

// ---------------- MFMA GEMM1: h1b[N,256] = bf16(x[N,128]) @ W1 + fused logits ----------------
// One block = 16 rows x 256 cols. Wave w covers cols [w*64, w*64+64) = head w.
__global__ __launch_bounds__(256) void gemm1_mfma(
    const float* __restrict__ x, const unsigned short* __restrict__ Wp,
    const float* __restrict__ att_s, const float* __restrict__ att_d,
    unsigned short* __restrict__ h1b,
    float* __restrict__ al_s, float* __restrict__ al_d, int N)
{
    __shared__ __align__(16) unsigned short As[16 * 136];  // K=128 pad->136
    const int tid = threadIdx.x;
    const int n0 = blockIdx.x * 16;
    const int l = tid & 63, w = tid >> 6;

    #pragma unroll
    for (int it = 0; it < 2; ++it) {
        int ch = tid + it * 256;            // 512 chunks of 4 floats
        int r = ch >> 5, c4 = (ch & 31) * 4;
        int row = n0 + r;
        float4 v = (row < N) ? ((const float4*)x)[(size_t)row * 32 + (c4 >> 2)]
                             : make_float4(0.f, 0.f, 0.f, 0.f);
        ushort4 pk = make_ushort4(f2bf_bits(v.x), f2bf_bits(v.y),
                                  f2bf_bits(v.z), f2bf_bits(v.w));
        *(ushort4*)&As[r * 136 + c4] = pk;
    }

    short8 bfr[4][4];
    #pragma unroll
    for (int t = 0; t < 4; ++t)
        #pragma unroll
        for (int p = 0; p < 4; ++p)
            bfr[t][p] = ((const short8*)Wp)[(t * 16 + (w * 4 + p)) * 64 + l];

    __syncthreads();

    f32x4 acc[4] = {{0.f,0.f,0.f,0.f},{0.f,0.f,0.f,0.f},
                    {0.f,0.f,0.f,0.f},{0.f,0.f,0.f,0.f}};
    #pragma unroll
    for (int t = 0; t < 4; ++t) {
        short8 a = *(const short8*)&As[(l & 15) * 136 + t * 32 + (l >> 4) * 8];
        #pragma unroll
        for (int p = 0; p < 4; ++p)
            acc[p] = __builtin_amdgcn_mfma_f32_16x16x32_bf16(a, bfr[t][p], acc[p], 0, 0, 0);
    }

    const int colbase = w * 64 + (l & 15);
    const int rowbase = n0 + (l >> 4) * 4;
    #pragma unroll
    for (int p = 0; p < 4; ++p) {
        int col = colbase + p * 16;
        #pragma unroll
        for (int r = 0; r < 4; ++r) {
            int row = rowbase + r;
            if (row < N) h1b[(size_t)row * D1 + col] = f2bf_bits(acc[p][r]);
        }
    }

    // fused attention logits: head == wave; reduce cols within 16-lane groups
    float as_p[4], ad_p[4];
    #pragma unroll
    for (int p = 0; p < 4; ++p) {
        as_p[p] = att_s[colbase + p * 16];
        ad_p[p] = att_d[colbase + p * 16];
    }
    #pragma unroll
    for (int r = 0; r < 4; ++r) {
        float ps = acc[0][r] * as_p[0] + acc[1][r] * as_p[1]
                 + acc[2][r] * as_p[2] + acc[3][r] * as_p[3];
        float pd = acc[0][r] * ad_p[0] + acc[1][r] * ad_p[1]
                 + acc[2][r] * ad_p[2] + acc[3][r] * ad_p[3];
        #pragma unroll
        for (int off = 8; off > 0; off >>= 1) {
            ps += __shfl_down(ps, off);
            pd += __shfl_down(pd, off);
        }
        int row = rowbase + r;
        if ((l & 15) == 0 && row < N) {
            al_s[(size_t)row * H1 + w] = ps;
            al_d[(size_t)row * H1 + w] = pd;
        }
    }
}

// ---------------- MFMA GEMM2: h2b[N,128] = hmidb[N,256] @ W2 + fused logits ----------------
// wave w covers cols [w*32, w*32+32); head = w>>1 (combine pairs via LDS).
__global__ __launch_bounds__(256) void gemm2_mfma(
    const unsigned short* __restrict__ hmidb, const unsigned short* __restrict__ Wp,
    const float* __restrict__ att_s, const float* __restrict__ att_d,
    unsigned short* __restrict__ h2b,
    float* __restrict__ al_s, float* __restrict__ al_d, int N)
{
    __shared__ __align__(16) unsigned short As[16 * 264];  // K=256 pad->264
    __shared__ float psL[4][16], pdL[4][16];
    const int tid = threadIdx.x;
    const int n0 = blockIdx.x * 16;
    const int l = tid & 63, w = tid >> 6;

    const short8 zero8 = {0,0,0,0,0,0,0,0};
    #pragma unroll
    for (int it = 0; it < 2; ++it) {
        int ch = tid + it * 256;            // 512 chunks of 8 bf16
        int r = ch >> 5, c8 = (ch & 31) * 8;
        int row = n0 + r;
        short8 v = (row < N) ? ((const short8*)hmidb)[(size_t)row * 32 + (ch & 31)] : zero8;
        *(short8*)&As[r * 264 + c8] = v;
    }

    short8 bfr[8][2];
    #pragma unroll
    for (int t = 0; t < 8; ++t)
        #pragma unroll
        for (int q = 0; q < 2; ++q)
            bfr[t][q] = ((const short8*)Wp)[(t * 8 + (w * 2 + q)) * 64 + l];

    __syncthreads();

    f32x4 acc[2] = {{0.f,0.f,0.f,0.f},{0.f,0.f,0.f,0.f}};
    #pragma unroll
    for (int t = 0; t < 8; ++t) {
        short8 a = *(const short8*)&As[(l & 15) * 264 + t * 32 + (l >> 4) * 8];
        #pragma unroll
        for (int q = 0; q < 2; ++q)
            acc[q] = __builtin_amdgcn_mfma_f32_16x16x32_bf16(a, bfr[t][q], acc[q], 0, 0, 0);
    }

    const int colbase = w * 32 + (l & 15);
    const int rowbase = n0 + (l >> 4) * 4;
    #pragma unroll
    for (int q = 0; q < 2; ++q) {
        int col = colbase + q * 16;
        #pragma unroll
        for (int r = 0; r < 4; ++r) {
            int row = rowbase + r;
            if (row < N) h2b[(size_t)row * D2 + col] = f2bf_bits(acc[q][r]);
        }
    }

    // fused logits: per-wave 32-col partials, combine wave pairs via LDS
    float as_q[2], ad_q[2];
    #pragma unroll
    for (int q = 0; q < 2; ++q) {
        as_q[q] = att_s[colbase + q * 16];
        ad_q[q] = att_d[colbase + q * 16];
    }
    #pragma unroll
    for (int r = 0; r < 4; ++r) {
        float ps = acc[0][r] * as_q[0] + acc[1][r] * as_q[1];
        float pd = acc[0][r] * ad_q[0] + acc[1][r] * ad_q[1];
        #pragma unroll
        for (int off = 8; off > 0; off >>= 1) {
            ps += __shfl_down(ps, off);
            pd += __shfl_down(pd, off);
        }
        if ((l & 15) == 0) {
            psL[w][(l >> 4) * 4 + r] = ps;
            pdL[w][(l >> 4) * 4 + r] = pd;
        }
    }
    __syncthreads();
    if (tid < 32) {
        int rl = tid & 15, hh = tid >> 4;
        int row = n0 + rl;
        if (row < N) {
            al_s[(size_t)row * H2 + hh] = psL[2*hh][rl] + psL[2*hh+1][rl];
            al_d[(size_t)row * H2 + hh] = pdL[2*hh][rl] + pdL[2*hh+1][rl];
        }
    }
}

// ---------------- Layer-1 aggregation: 64 thr, 4 ch/thread, 4x ILP + LN + ELU ----------------
// thread t owns channels 4t..4t+3; head = t>>4 (64 ch/head). Per-thread running
// denom is the softmax denominator (w replicated across the head's 16 lanes).
__global__ __launch_bounds__(64) void agg1_kernel(
    const int* __restrict__ rowptr, const int* __restrict__ csr_src,
    const uint2* __restrict__ h1p,   // [N,64] packed bf16x4
    const float* __restrict__ al_s, const float* __restrict__ al_d,
    const float* __restrict__ b1,
    const float* __restrict__ ln_w, const float* __restrict__ ln_b,
    uint2* __restrict__ hmidp, int N)  // [N,64] packed bf16x4 out
{
    const int n = blockIdx.x;
    const int t = threadIdx.x;
    const int h = t >> 4;
    const float ad = al_d[(size_t)n * H1 + h];

    float a0[4] = {0.f,0.f,0.f,0.f}, a1[4] = {0.f,0.f,0.f,0.f};
    float a2[4] = {0.f,0.f,0.f,0.f}, a3[4] = {0.f,0.f,0.f,0.f};
    float dn0, dn1 = 0.f, dn2 = 0.f, dn3 = 0.f;

    // self loop
    {
        float w = edge_w<H1>(al_s, n, ad, h);
        uint2 p = h1p[(size_t)n * 64 + t];
        float2 va = unpack_bf2(p.x), vb = unpack_bf2(p.y);
        a0[0] = w * va.x; a0[1] = w * va.y; a0[2] = w * vb.x; a0[3] = w * vb.y;
        dn0 = w;
    }

    const int beg = rowptr[n], end = rowptr[n + 1];
    int i = beg;
    for (; i + 4 <= end; i += 4) {
        int s0 = csr_src[i], s1 = csr_src[i+1], s2 = csr_src[i+2], s3 = csr_src[i+3];
        uint2 p0 = h1p[(size_t)s0 * 64 + t];
        uint2 p1 = h1p[(size_t)s1 * 64 + t];
        uint2 p2 = h1p[(size_t)s2 * 64 + t];
        uint2 p3 = h1p[(size_t)s3 * 64 + t];
        float w0 = edge_w<H1>(al_s, s0, ad, h);
        float w1 = edge_w<H1>(al_s, s1, ad, h);
        float w2 = edge_w<H1>(al_s, s2, ad, h);
        float w3 = edge_w<H1>(al_s, s3, ad, h);
        float2 v0a = unpack_bf2(p0.x), v0b = unpack_bf2(p0.y);
        float2 v1a = unpack_bf2(p1.x), v1b = unpack_bf2(p1.y);
        float2 v2a = unpack_bf2(p2.x), v2b = unpack_bf2(p2.y);
        float2 v3a = unpack_bf2(p3.x), v3b = unpack_bf2(p3.y);
        a0[0] += w0 * v0a.x; a0[1] += w0 * v0a.y; a0[2] += w0 * v0b.x; a0[3] += w0 * v0b.y; dn0 += w0;
        a1[0] += w1 * v1a.x; a1[1] += w1 * v1a.y; a1[2] += w1 * v1b.x; a1[3] += w1 * v1b.y; dn1 += w1;
        a2[0] += w2 * v2a.x; a2[1] += w2 * v2a.y; a2[2] += w2 * v2b.x; a2[3] += w2 * v2b.y; dn2 += w2;
        a3[0] += w3 * v3a.x; a3[1] += w3 * v3a.y; a3[2] += w3 * v3b.x; a3[3] += w3 * v3b.y; dn3 += w3;
    }
    for (; i < end; ++i) {
        int s0 = csr_src[i];
        uint2 p0 = h1p[(size_t)s0 * 64 + t];
        float w0 = edge_w<H1>(al_s, s0, ad, h);
        float2 v0a = unpack_bf2(p0.x), v0b = unpack_bf2(p0.y);
        a0[0] += w0 * v0a.x; a0[1] += w0 * v0a.y; a0[2] += w0 * v0b.x; a0[3] += w0 * v0b.y; dn0 += w0;
    }

    const float inv = 1.f / ((dn0 + dn1) + (dn2 + dn3));
    float4 bb = ((const float4*)b1)[t];
    float v[4];
    v[0] = ((a0[0]+a1[0]) + (a2[0]+a3[0])) * inv + bb.x;
    v[1] = ((a0[1]+a1[1]) + (a2[1]+a3[1])) * inv + bb.y;
    v[2] = ((a0[2]+a1[2]) + (a2[2]+a3[2])) * inv + bb.z;
    v[3] = ((a0[3]+a1[3]) + (a2[3]+a3[3])) * inv + bb.w;

    // LayerNorm over 256 channels: single-wave shfl reduction
    float s  = (v[0]+v[1]) + (v[2]+v[3]);
    float s2 = (v[0]*v[0]+v[1]*v[1]) + (v[2]*v[2]+v[3]*v[3]);
    #pragma unroll
    for (int off = 32; off > 0; off >>= 1) {
        s  += __shfl_down(s,  off);
        s2 += __shfl_down(s2, off);
    }
    const float mu   = __shfl(s,  0) * (1.f / 256.f);
    const float ex2  = __shfl(s2, 0) * (1.f / 256.f);
    const float rstd = rsqrtf(ex2 - mu * mu + LN_EPS);
    float4 lw = ((const float4*)ln_w)[t];
    float4 lb = ((const float4*)ln_b)[t];
    float y0 = (v[0] - mu) * rstd * lw.x + lb.x;
    float y1 = (v[1] - mu) * rstd * lw.y + lb.y;
    float y2 = (v[2] - mu) * rstd * lw.z + lb.z;
    float y3 = (v[3] - mu) * rstd * lw.w + lb.w;
    y0 = y0 > 0.f ? y0 : (__expf(y0) - 1.f);
    y1 = y1 > 0.f ? y1 : (__expf(y1) - 1.f);
    y2 = y2 > 0.f ? y2 : (__expf(y2) - 1.f);
    y3 = y3 > 0.f ? y3 : (__expf(y3) - 1.f);
    uint2 outp;
    outp.x = pack_bf2(y0, y1);
    outp.y = pack_bf2(y2, y3);
    hmidp[(size_t)n * 64 + t] = outp;
}

// ---------------- Layer-2 aggregation (bf16 gather, 4x unroll) + head-mean ----------------
__global__ __launch_bounds__(64) void agg2_kernel(
    const int* __restrict__ rowptr, const int* __restrict__ csr_src,
    const unsigned int* __restrict__ h2p,   // [N,64] packed bf16x2
    const float* __restrict__ al_s, const float* __restrict__ al_d,
    const float* __restrict__ b2,
    float* __restrict__ out, int N)
{
    const int n = blockIdx.x;
    const int t = threadIdx.x;
    const int h = t >> 5;
    const float ad = al_d[(size_t)n * H2 + h];

    const float ws = edge_w<H2>(al_s, n, ad, h);
    float2 hv = unpack_bf2(h2p[(size_t)n * 64 + t]);
    float ax0 = ws * hv.x, ay0 = ws * hv.y, dn0 = ws;
    float ax1 = 0.f, ay1 = 0.f, dn1 = 0.f;
    float ax2 = 0.f, ay2 = 0.f, dn2 = 0.f;
    float ax3 = 0.f, ay3 = 0.f, dn3 = 0.f;

    const int beg = rowptr[n], end = rowptr[n + 1];
    int i = beg;
    for (; i + 4 <= end; i += 4) {
        int s0 = csr_src[i], s1 = csr_src[i+1], s2 = csr_src[i+2], s3 = csr_src[i+3];
        unsigned int p0 = h2p[(size_t)s0 * 64 + t];
        unsigned int p1 = h2p[(size_t)s1 * 64 + t];
        unsigned int p2 = h2p[(size_t)s2 * 64 + t];
        unsigned int p3 = h2p[(size_t)s3 * 64 + t];
        float w0 = edge_w<H2>(al_s, s0, ad, h);
        float w1 = edge_w<H2>(al_s, s1, ad, h);
        float w2 = edge_w<H2>(al_s, s2, ad, h);
        float w3 = edge_w<H2>(al_s, s3, ad, h);
        float2 v0 = unpack_bf2(p0), v1 = unpack_bf2(p1);
        float2 v2 = unpack_bf2(p2), v3 = unpack_bf2(p3);
        ax0 += w0 * v0.x; ay0 += w0 * v0.y; dn0 += w0;
        ax1 += w1 * v1.x; ay1 += w1 * v1.y; dn1 += w1;
        ax2 += w2 * v2.x; ay2 += w2 * v2.y; dn2 += w2;
        ax3 += w3 * v3.x; ay3 += w3 * v3.y; dn3 += w3;
    }
    for (; i < end; ++i) {
        int s0 = csr_src[i];
        unsigned int p0 = h2p[(size_t)s0 * 64 + t];
        float w0 = edge_w<H2>(al_s, s0, ad, h);
        float2 v0 = unpack_bf2(p0);
        ax0 += w0 * v0.x; ay0 += w0 * v0.y; dn0 += w0;
    }

    const float inv = 1.f / ((dn0 + dn1) + (dn2 + dn3));
    const float vx = ((ax0 + ax1) + (ax2 + ax3)) * inv;
    const float vy = ((ay0 + ay1) + (ay2 + ay3)) * inv;

    __shared__ float sv[128];
    sv[2 * t]     = vx;
    sv[2 * t + 1] = vy;
    __syncthreads();
    out[(size_t)n * OUT_DIM + t] = 0.5f * (sv[t] + sv[64 + t]) + b2[t];
}

extern "C" void kernel_launch(void* const* d_in, const int* in_sizes, int n_in,
                              void* d_out, int out_size, void* d_ws, size_t ws_size,
                              hipStream_t stream)
{
    const float* x   = (const float*)d_in[0];
    const int*   ei  = (const int*)d_in[1];
    const float* W1  = (const float*)d_in[2];
    const float* as1 = (const float*)d_in[3];
    const float* ad1 = (const float*)d_in[4];
    const float* b1  = (const float*)d_in[5];
    const float* lnw = (const float*)d_in[6];
    const float* lnb = (const float*)d_in[7];
    const float* W2  = (const float*)d_in[8];
    const float* as2 = (const float*)d_in[9];
    const float* ad2 = (const float*)d_in[10];
    const float* b2  = (const float*)d_in[11];

    const int N = in_sizes[0] / IN_DIM;   // 50000
    const int E = in_sizes[1] / 2;        // 800000

    char* ws = (char*)d_ws;
    const size_t szH1b = (size_t)N * D1 * sizeof(unsigned short);
    unsigned short* h1b   = (unsigned short*)(ws);
    unsigned short* hmidb = (unsigned short*)(ws + szH1b);
    unsigned short* Wp1   = (unsigned short*)(ws + 2 * szH1b);
    unsigned short* Wp2   = Wp1 + 32768;
    float* al_s1 = (float*)(Wp2 + 32768);
    float* al_d1 = al_s1 + (size_t)N * H1;
    float* al_s2 = al_d1 + (size_t)N * H1;
    float* al_d2 = al_s2 + (size_t)N * H2;
    int* deg     = (int*)(al_d2 + (size_t)N * H2);
    int* rowptr  = deg + (N + 1);
    int* cursor  = rowptr + (N + 1);
    int* csr_src = cursor + (N + 1);
    int* bsum    = csr_src + E;
    unsigned short* h2b = h1b;   // reuse after agg1 consumed h1b

    hipMemsetAsync(deg, 0, (size_t)(N + 1) * sizeof(int), stream);

    const int edgeBlocks = (E + 255) / 256;
    const int scanBlocks = (N + 255) / 256;
    const int tileBlocks = (N + 15) / 16;

    conv_weights<<<256, 256, 0, stream>>>(W1, W2, Wp1, Wp2);
    hist_kernel<<<edgeBlocks, 256, 0, stream>>>(ei, E, deg);
    scan_partial<<<scanBlocks, 256, 0, stream>>>(deg, N, bsum);
    scan_top<<<1, 256, 0, stream>>>(bsum, scanBlocks, rowptr + N);
    scan_final<<<scanBlocks, 256, 0, stream>>>(deg, bsum, N, rowptr, cursor);
    fill_kernel<<<edgeBlocks, 256, 0, stream>>>(ei, E, cursor, csr_src);

    gemm1_mfma<<<tileBlocks, 256, 0, stream>>>(x, Wp1, as1, ad1, h1b, al_s1, al_d1, N);
    agg1_kernel<<<N, 64, 0, stream>>>(rowptr, csr_src, (const uint2*)h1b,
                                      al_s1, al_d1, b1, lnw, lnb,
                                      (uint2*)hmidb, N);
    gemm2_mfma<<<tileBlocks, 256, 0, stream>>>(hmidb, Wp2, as2, ad2, h2b, al_s2, al_d2, N);
    agg2_kernel<<<N, 64, 0, stream>>>(rowptr, csr_src, (const unsigned int*)h2b,
                                      al_s2, al_d2, b2, (float*)d_out, N);
}

// Round 7
// 314.007 us; speedup vs baseline: 4.5372x; 1.0135x over previous
//
#include <hip/hip_runtime.h>
#include <hip/hip_bf16.h>
#include <math.h>

#define IN_DIM  128
#define HID     64
#define H1      4
#define H2      2
#define OUT_DIM 64
#define D1      256   // H1*HID
#define D2      128   // H2*OUT_DIM
#define LRELU   0.2f
#define LN_EPS  1e-5f

using short8 = __attribute__((ext_vector_type(8))) short;
using f32x4  = __attribute__((ext_vector_type(4))) float;

static __device__ __forceinline__ unsigned short f2bf_bits(float f)
{
    __hip_bfloat16 b = __float2bfloat16(f);
    return *reinterpret_cast<unsigned short*>(&b);
}
static __device__ __forceinline__ float2 unpack_bf2(unsigned int p)
{
    float2 r;
    r.x = __uint_as_float(p << 16);
    r.y = __uint_as_float(p & 0xffff0000u);
    return r;
}
static __device__ __forceinline__ unsigned int pack_bf2(float x, float y)
{
    return (unsigned int)f2bf_bits(x) | ((unsigned int)f2bf_bits(y) << 16);
}

template<int H>
static __device__ __forceinline__ float edge_w(
    const float* __restrict__ al_s, int src, float ad, int h)
{
    float v = al_s[(size_t)src * H + h] + ad;
    v = v > 0.f ? v : LRELU * v;
    return __expf(v);
}

// inline int64-vs-int32 edge_index probe: int64 data has zero odd words.
static __device__ __forceinline__ int detect_i64(const int* __restrict__ ei)
{
    int any_odd_nonzero = 0;
    #pragma unroll
    for (int k = 1; k < 16; k += 2) any_odd_nonzero |= (ei[k] != 0);
    return any_odd_nonzero ? 0 : 1;
}

// ---------------- fused weight pre-pack + degree histogram ----------------
// blocks [0,256): pack W1/W2 into MFMA B-fragment order.
// blocks [256, 256+edgeBlocks): histogram dst degrees.
__global__ __launch_bounds__(256) void conv_hist_kernel(
    const float* __restrict__ W1, const float* __restrict__ W2,
    unsigned short* __restrict__ Wp1, unsigned short* __restrict__ Wp2,
    const int* __restrict__ ei, int E, int* __restrict__ deg)
{
    const int bid = blockIdx.x;
    if (bid < 256) {
        int tid = bid * 256 + threadIdx.x;   // 0..65535
        if (tid < 32768) {                   // W1: 4 ksteps x 16 stripes
            int j = tid & 7, l = (tid >> 3) & 63, rest = tid >> 9;
            int s = rest & 15, t = rest >> 4;
            int k = t * 32 + (l >> 4) * 8 + j, col = s * 16 + (l & 15);
            Wp1[tid] = f2bf_bits(W1[k * D1 + col]);
        } else {                             // W2: 8 ksteps x 8 stripes
            int id = tid - 32768;
            int j = id & 7, l = (id >> 3) & 63, rest = id >> 9;
            int s = rest & 7, t = rest >> 3;
            int k = t * 32 + (l >> 4) * 8 + j, col = s * 16 + (l & 15);
            Wp2[id] = f2bf_bits(W2[k * D2 + col]);
        }
    } else {
        const int i64f = detect_i64(ei);
        int e = (bid - 256) * 256 + threadIdx.x;
        if (e >= E) return;
        int dst = i64f ? ei[2 * ((size_t)E + e)] : ei[E + e];
        atomicAdd(&deg[dst], 1);
    }
}

__global__ __launch_bounds__(256) void scan_partial(
    const int* __restrict__ deg, int N, int* __restrict__ bsum)
{
    __shared__ int s[256];
    int i = blockIdx.x * 256 + threadIdx.x;
    s[threadIdx.x] = (i < N) ? deg[i] : 0;
    __syncthreads();
    for (int st = 128; st > 0; st >>= 1) {
        if (threadIdx.x < st) s[threadIdx.x] += s[threadIdx.x + st];
        __syncthreads();
    }
    if (threadIdx.x == 0) bsum[blockIdx.x] = s[0];
}

// Each block re-scans bsum[0..B) in LDS (cheap), then does its local scan.
__global__ __launch_bounds__(256) void scan_final(
    const int* __restrict__ deg, const int* __restrict__ bsum, int B, int N, int E,
    int* __restrict__ rowptr, int* __restrict__ cursor)
{
    __shared__ int sb[256];
    __shared__ int s[256];
    sb[threadIdx.x] = (threadIdx.x < B) ? bsum[threadIdx.x] : 0;
    __syncthreads();
    for (int st = 1; st < 256; st <<= 1) {
        int t = (threadIdx.x >= st) ? sb[threadIdx.x - st] : 0;
        __syncthreads();
        sb[threadIdx.x] += t;
        __syncthreads();
    }
    const int blockOff = (blockIdx.x == 0) ? 0 : sb[blockIdx.x - 1];

    int i = blockIdx.x * 256 + threadIdx.x;
    int v = (i < N) ? deg[i] : 0;
    s[threadIdx.x] = v;
    __syncthreads();
    for (int st = 1; st < 256; st <<= 1) {
        int t = (threadIdx.x >= st) ? s[threadIdx.x - st] : 0;
        __syncthreads();
        s[threadIdx.x] += t;
        __syncthreads();
    }
    int excl = s[threadIdx.x] - v + blockOff;
    if (i < N) { rowptr[i] = excl; cursor[i] = excl; }
    if (blockIdx.x == 0 && threadIdx.x == 0) rowptr[N] = E;
}

__global__ __launch_bounds__(256) void fill_kernel(
    const int* __restrict__ ei, int E,
    int* __restrict__ cursor, int* __restrict__ csr_src)
{
    const int i64f = detect_i64(ei);
    int e = blockIdx.x * 256 + threadIdx.x;
    if (e >= E) return;
    int src, dst;
    if (i64f) { src = ei[2 * (size_t)e]; dst = ei[2 * ((size_t)E + e)]; }
    else      { src = ei[e];             dst = ei[E + e]; }
    int pos = atomicAdd(&cursor[dst], 1);
    csr_src[pos] = src;
}

// ---------------- MFMA GEMM1: h1b[N,256] = bf16(x[N,128]) @ W1 + fused logits ----------------
// One block = 16 rows x 256 cols. Wave w covers cols [w*64, w*64+64) = head w.
__global__ __launch_bounds__(256) void gemm1_mfma(
    const float* __restrict__ x, const unsigned short* __restrict__ Wp,
    const float* __restrict__ att_s, const float* __restrict__ att_d,
    unsigned short* __restrict__ h1b,
    float* __restrict__ al_s, float* __restrict__ al_d, int N)
{
    __shared__ __align__(16) unsigned short As[16 * 136];  // K=128 pad->136
    const int tid = threadIdx.x;
    const int n0 = blockIdx.x * 16;
    const int l = tid & 63, w = tid >> 6;

    #pragma unroll
    for (int it = 0; it < 2; ++it) {
        int ch = tid + it * 256;            // 512 chunks of 4 floats
        int r = ch >> 5, c4 = (ch & 31) * 4;
        int row = n0 + r;
        float4 v = (row < N) ? ((const float4*)x)[(size_t)row * 32 + (c4 >> 2)]
                             : make_float4(0.f, 0.f, 0.f, 0.f);
        ushort4 pk = make_ushort4(f2bf_bits(v.x), f2bf_bits(v.y),
                                  f2bf_bits(v.z), f2bf_bits(v.w));
        *(ushort4*)&As[r * 136 + c4] = pk;
    }

    short8 bfr[4][4];
    #pragma unroll
    for (int t = 0; t < 4; ++t)
        #pragma unroll
        for (int p = 0; p < 4; ++p)
            bfr[t][p] = ((const short8*)Wp)[(t * 16 + (w * 4 + p)) * 64 + l];

    __syncthreads();

    f32x4 acc[4] = {{0.f,0.f,0.f,0.f},{0.f,0.f,0.f,0.f},
                    {0.f,0.f,0.f,0.f},{0.f,0.f,0.f,0.f}};
    #pragma unroll
    for (int t = 0; t < 4; ++t) {
        short8 a = *(const short8*)&As[(l & 15) * 136 + t * 32 + (l >> 4) * 8];
        #pragma unroll
        for (int p = 0; p < 4; ++p)
            acc[p] = __builtin_amdgcn_mfma_f32_16x16x32_bf16(a, bfr[t][p], acc[p], 0, 0, 0);
    }

    const int colbase = w * 64 + (l & 15);
    const int rowbase = n0 + (l >> 4) * 4;
    #pragma unroll
    for (int p = 0; p < 4; ++p) {
        int col = colbase + p * 16;
        #pragma unroll
        for (int r = 0; r < 4; ++r) {
            int row = rowbase + r;
            if (row < N) h1b[(size_t)row * D1 + col] = f2bf_bits(acc[p][r]);
        }
    }

    // fused attention logits: head == wave; reduce cols within 16-lane groups
    float as_p[4], ad_p[4];
    #pragma unroll
    for (int p = 0; p < 4; ++p) {
        as_p[p] = att_s[colbase + p * 16];
        ad_p[p] = att_d[colbase + p * 16];
    }
    #pragma unroll
    for (int r = 0; r < 4; ++r) {
        float ps = acc[0][r] * as_p[0] + acc[1][r] * as_p[1]
                 + acc[2][r] * as_p[2] + acc[3][r] * as_p[3];
        float pd = acc[0][r] * ad_p[0] + acc[1][r] * ad_p[1]
                 + acc[2][r] * ad_p[2] + acc[3][r] * ad_p[3];
        #pragma unroll
        for (int off = 8; off > 0; off >>= 1) {
            ps += __shfl_down(ps, off);
            pd += __shfl_down(pd, off);
        }
        int row = rowbase + r;
        if ((l & 15) == 0 && row < N) {
            al_s[(size_t)row * H1 + w] = ps;
            al_d[(size_t)row * H1 + w] = pd;
        }
    }
}

// ---------------- MFMA GEMM2: h2b[N,128] = hmidb[N,256] @ W2 + fused logits ----------------
__global__ __launch_bounds__(256) void gemm2_mfma(
    const unsigned short* __restrict__ hmidb, const unsigned short* __restrict__ Wp,
    const float* __restrict__ att_s, const float* __restrict__ att_d,
    unsigned short* __restrict__ h2b,
    float* __restrict__ al_s, float* __restrict__ al_d, int N)
{
    __shared__ __align__(16) unsigned short As[16 * 264];  // K=256 pad->264
    __shared__ float psL[4][16], pdL[4][16];
    const int tid = threadIdx.x;
    const int n0 = blockIdx.x * 16;
    const int l = tid & 63, w = tid >> 6;

    const short8 zero8 = {0,0,0,0,0,0,0,0};
    #pragma unroll
    for (int it = 0; it < 2; ++it) {
        int ch = tid + it * 256;            // 512 chunks of 8 bf16
        int r = ch >> 5, c8 = (ch & 31) * 8;
        int row = n0 + r;
        short8 v = (row < N) ? ((const short8*)hmidb)[(size_t)row * 32 + (ch & 31)] : zero8;
        *(short8*)&As[r * 264 + c8] = v;
    }

    short8 bfr[8][2];
    #pragma unroll
    for (int t = 0; t < 8; ++t)
        #pragma unroll
        for (int q = 0; q < 2; ++q)
            bfr[t][q] = ((const short8*)Wp)[(t * 8 + (w * 2 + q)) * 64 + l];

    __syncthreads();

    f32x4 acc[2] = {{0.f,0.f,0.f,0.f},{0.f,0.f,0.f,0.f}};
    #pragma unroll
    for (int t = 0; t < 8; ++t) {
        short8 a = *(const short8*)&As[(l & 15) * 264 + t * 32 + (l >> 4) * 8];
        #pragma unroll
        for (int q = 0; q < 2; ++q)
            acc[q] = __builtin_amdgcn_mfma_f32_16x16x32_bf16(a, bfr[t][q], acc[q], 0, 0, 0);
    }

    const int colbase = w * 32 + (l & 15);
    const int rowbase = n0 + (l >> 4) * 4;
    #pragma unroll
    for (int q = 0; q < 2; ++q) {
        int col = colbase + q * 16;
        #pragma unroll
        for (int r = 0; r < 4; ++r) {
            int row = rowbase + r;
            if (row < N) h2b[(size_t)row * D2 + col] = f2bf_bits(acc[q][r]);
        }
    }

    float as_q[2], ad_q[2];
    #pragma unroll
    for (int q = 0; q < 2; ++q) {
        as_q[q] = att_s[colbase + q * 16];
        ad_q[q] = att_d[colbase + q * 16];
    }
    #pragma unroll
    for (int r = 0; r < 4; ++r) {
        float ps = acc[0][r] * as_q[0] + acc[1][r] * as_q[1];
        float pd = acc[0][r] * ad_q[0] + acc[1][r] * ad_q[1];
        #pragma unroll
        for (int off = 8; off > 0; off >>= 1) {
            ps += __shfl_down(ps, off);
            pd += __shfl_down(pd, off);
        }
        if ((l & 15) == 0) {
            psL[w][(l >> 4) * 4 + r] = ps;
            pdL[w][(l >> 4) * 4 + r] = pd;
        }
    }
    __syncthreads();
    if (tid < 32) {
        int rl = tid & 15, hh = tid >> 4;
        int row = n0 + rl;
        if (row < N) {
            al_s[(size_t)row * H2 + hh] = psL[2*hh][rl] + psL[2*hh+1][rl];
            al_d[(size_t)row * H2 + hh] = pdL[2*hh][rl] + pdL[2*hh+1][rl];
        }
    }
}

// ---------------- Layer-1 aggregation: 64 thr, 4 ch/thread, 8x-unrolled gather + LN + ELU ----
// thread t owns channels 4t..4t+3; head = t>>4. Per-thread running denom IS the
// softmax denominator (w replicated across the head's 16 lanes).
__global__ __launch_bounds__(64) void agg1_kernel(
    const int* __restrict__ rowptr, const int* __restrict__ csr_src,
    const uint2* __restrict__ h1p,   // [N,64] packed bf16x4
    const float* __restrict__ al_s, const float* __restrict__ al_d,
    const float* __restrict__ b1,
    const float* __restrict__ ln_w, const float* __restrict__ ln_b,
    uint2* __restrict__ hmidp, int N)  // [N,64] packed bf16x4 out
{
    const int n = blockIdx.x;
    const int t = threadIdx.x;
    const int h = t >> 4;
    const float ad = al_d[(size_t)n * H1 + h];

    float a0[4] = {0.f,0.f,0.f,0.f}, a1[4] = {0.f,0.f,0.f,0.f};
    float a2[4] = {0.f,0.f,0.f,0.f}, a3[4] = {0.f,0.f,0.f,0.f};
    float dn0, dn1 = 0.f, dn2 = 0.f, dn3 = 0.f;

    {   // self loop
        float w = edge_w<H1>(al_s, n, ad, h);
        uint2 p = h1p[(size_t)n * 64 + t];
        float2 va = unpack_bf2(p.x), vb = unpack_bf2(p.y);
        a0[0] = w * va.x; a0[1] = w * va.y; a0[2] = w * vb.x; a0[3] = w * vb.y;
        dn0 = w;
    }

    const int beg = rowptr[n], end = rowptr[n + 1];
    int i = beg;

#define LOADE1(k) int s##k = csr_src[i + k]; \
                  uint2 p##k = h1p[(size_t)s##k * 64 + t]; \
                  float w##k = edge_w<H1>(al_s, s##k, ad, h);
#define ACC1(A, D, k) { float2 va = unpack_bf2(p##k.x), vb = unpack_bf2(p##k.y); \
                        A[0] += w##k * va.x; A[1] += w##k * va.y; \
                        A[2] += w##k * vb.x; A[3] += w##k * vb.y; D += w##k; }

    for (; i + 8 <= end; i += 8) {
        LOADE1(0) LOADE1(1) LOADE1(2) LOADE1(3)
        LOADE1(4) LOADE1(5) LOADE1(6) LOADE1(7)
        ACC1(a0, dn0, 0) ACC1(a1, dn1, 1) ACC1(a2, dn2, 2) ACC1(a3, dn3, 3)
        ACC1(a0, dn0, 4) ACC1(a1, dn1, 5) ACC1(a2, dn2, 6) ACC1(a3, dn3, 7)
    }
    for (; i + 4 <= end; i += 4) {
        LOADE1(0) LOADE1(1) LOADE1(2) LOADE1(3)
        ACC1(a0, dn0, 0) ACC1(a1, dn1, 1) ACC1(a2, dn2, 2) ACC1(a3, dn3, 3)
    }
    for (; i < end; ++i) {
        LOADE1(0) ACC1(a0, dn0, 0)
    }
#undef LOADE1
#undef ACC1

    const float inv = 1.f / ((dn0 + dn1) + (dn2 + dn3));
    float4 bb = ((const float4*)b1)[t];
    float v[4];
    v[0] = ((a0[0]+a1[0]) + (a2[0]+a3[0])) * inv + bb.x;
    v[1] = ((a0[1]+a1[1]) + (a2[1]+a3[1])) * inv + bb.y;
    v[2] = ((a0[2]+a1[2]) + (a2[2]+a3[2])) * inv + bb.z;
    v[3] = ((a0[3]+a1[3]) + (a2[3]+a3[3])) * inv + bb.w;

    // LayerNorm over 256 channels: single-wave shfl reduction
    float s  = (v[0]+v[1]) + (v[2]+v[3]);
    float s2 = (v[0]*v[0]+v[1]*v[1]) + (v[2]*v[2]+v[3]*v[3]);
    #pragma unroll
    for (int off = 32; off > 0; off >>= 1) {
        s  += __shfl_down(s,  off);
        s2 += __shfl_down(s2, off);
    }
    const float mu   = __shfl(s,  0) * (1.f / 256.f);
    const float ex2  = __shfl(s2, 0) * (1.f / 256.f);
    const float rstd = rsqrtf(ex2 - mu * mu + LN_EPS);
    float4 lw = ((const float4*)ln_w)[t];
    float4 lb = ((const float4*)ln_b)[t];
    float y0 = (v[0] - mu) * rstd * lw.x + lb.x;
    float y1 = (v[1] - mu) * rstd * lw.y + lb.y;
    float y2 = (v[2] - mu) * rstd * lw.z + lb.z;
    float y3 = (v[3] - mu) * rstd * lw.w + lb.w;
    y0 = y0 > 0.f ? y0 : (__expf(y0) - 1.f);
    y1 = y1 > 0.f ? y1 : (__expf(y1) - 1.f);
    y2 = y2 > 0.f ? y2 : (__expf(y2) - 1.f);
    y3 = y3 > 0.f ? y3 : (__expf(y3) - 1.f);
    uint2 outp;
    outp.x = pack_bf2(y0, y1);
    outp.y = pack_bf2(y2, y3);
    hmidp[(size_t)n * 64 + t] = outp;
}

// ---------------- Layer-2 aggregation: 64 thr, 2 ch/thread, 8x-unrolled + head-mean ---------
__global__ __launch_bounds__(64) void agg2_kernel(
    const int* __restrict__ rowptr, const int* __restrict__ csr_src,
    const unsigned int* __restrict__ h2p,   // [N,64] packed bf16x2
    const float* __restrict__ al_s, const float* __restrict__ al_d,
    const float* __restrict__ b2,
    float* __restrict__ out, int N)
{
    const int n = blockIdx.x;
    const int t = threadIdx.x;
    const int h = t >> 5;
    const float ad = al_d[(size_t)n * H2 + h];

    float ax0, ay0, dn0;
    float ax1 = 0.f, ay1 = 0.f, dn1 = 0.f;
    float ax2 = 0.f, ay2 = 0.f, dn2 = 0.f;
    float ax3 = 0.f, ay3 = 0.f, dn3 = 0.f;
    {
        float w = edge_w<H2>(al_s, n, ad, h);
        float2 hv = unpack_bf2(h2p[(size_t)n * 64 + t]);
        ax0 = w * hv.x; ay0 = w * hv.y; dn0 = w;
    }

    const int beg = rowptr[n], end = rowptr[n + 1];
    int i = beg;

#define LOADE2(k) int s##k = csr_src[i + k]; \
                  unsigned int p##k = h2p[(size_t)s##k * 64 + t]; \
                  float w##k = edge_w<H2>(al_s, s##k, ad, h);
#define ACC2(AX, AY, D, k) { float2 vv = unpack_bf2(p##k); \
                             AX += w##k * vv.x; AY += w##k * vv.y; D += w##k; }

    for (; i + 8 <= end; i += 8) {
        LOADE2(0) LOADE2(1) LOADE2(2) LOADE2(3)
        LOADE2(4) LOADE2(5) LOADE2(6) LOADE2(7)
        ACC2(ax0, ay0, dn0, 0) ACC2(ax1, ay1, dn1, 1)
        ACC2(ax2, ay2, dn2, 2) ACC2(ax3, ay3, dn3, 3)
        ACC2(ax0, ay0, dn0, 4) ACC2(ax1, ay1, dn1, 5)
        ACC2(ax2, ay2, dn2, 6) ACC2(ax3, ay3, dn3, 7)
    }
    for (; i + 4 <= end; i += 4) {
        LOADE2(0) LOADE2(1) LOADE2(2) LOADE2(3)
        ACC2(ax0, ay0, dn0, 0) ACC2(ax1, ay1, dn1, 1)
        ACC2(ax2, ay2, dn2, 2) ACC2(ax3, ay3, dn3, 3)
    }
    for (; i < end; ++i) {
        LOADE2(0) ACC2(ax0, ay0, dn0, 0)
    }
#undef LOADE2
#undef ACC2

    const float inv = 1.f / ((dn0 + dn1) + (dn2 + dn3));
    const float vx = ((ax0 + ax1) + (ax2 + ax3)) * inv;
    const float vy = ((ay0 + ay1) + (ay2 + ay3)) * inv;

    __shared__ float sv[128];
    sv[2 * t]     = vx;
    sv[2 * t + 1] = vy;
    __syncthreads();
    out[(size_t)n * OUT_DIM + t] = 0.5f * (sv[t] + sv[64 + t]) + b2[t];
}

extern "C" void kernel_launch(void* const* d_in, const int* in_sizes, int n_in,
                              void* d_out, int out_size, void* d_ws, size_t ws_size,
                              hipStream_t stream)
{
    const float* x   = (const float*)d_in[0];
    const int*   ei  = (const int*)d_in[1];
    const float* W1  = (const float*)d_in[2];
    const float* as1 = (const float*)d_in[3];
    const float* ad1 = (const float*)d_in[4];
    const float* b1  = (const float*)d_in[5];
    const float* lnw = (const float*)d_in[6];
    const float* lnb = (const float*)d_in[7];
    const float* W2  = (const float*)d_in[8];
    const float* as2 = (const float*)d_in[9];
    const float* ad2 = (const float*)d_in[10];
    const float* b2  = (const float*)d_in[11];

    const int N = in_sizes[0] / IN_DIM;   // 50000
    const int E = in_sizes[1] / 2;        // 800000

    char* ws = (char*)d_ws;
    const size_t szH1b = (size_t)N * D1 * sizeof(unsigned short);
    unsigned short* h1b   = (unsigned short*)(ws);
    unsigned short* hmidb = (unsigned short*)(ws + szH1b);
    unsigned short* Wp1   = (unsigned short*)(ws + 2 * szH1b);
    unsigned short* Wp2   = Wp1 + 32768;
    float* al_s1 = (float*)(Wp2 + 32768);
    float* al_d1 = al_s1 + (size_t)N * H1;
    float* al_s2 = al_d1 + (size_t)N * H1;
    float* al_d2 = al_s2 + (size_t)N * H2;
    int* deg     = (int*)(al_d2 + (size_t)N * H2);
    int* rowptr  = deg + (N + 1);
    int* cursor  = rowptr + (N + 1);
    int* csr_src = cursor + (N + 1);
    int* bsum    = csr_src + E;
    unsigned short* h2b = h1b;   // reuse after agg1 consumed h1b

    hipMemsetAsync(deg, 0, (size_t)(N + 1) * sizeof(int), stream);

    const int edgeBlocks = (E + 255) / 256;
    const int scanBlocks = (N + 255) / 256;   // 196 <= 256
    const int tileBlocks = (N + 15) / 16;

    conv_hist_kernel<<<256 + edgeBlocks, 256, 0, stream>>>(W1, W2, Wp1, Wp2, ei, E, deg);
    scan_partial<<<scanBlocks, 256, 0, stream>>>(deg, N, bsum);
    scan_final<<<scanBlocks, 256, 0, stream>>>(deg, bsum, scanBlocks, N, E, rowptr, cursor);
    fill_kernel<<<edgeBlocks, 256, 0, stream>>>(ei, E, cursor, csr_src);

    gemm1_mfma<<<tileBlocks, 256, 0, stream>>>(x, Wp1, as1, ad1, h1b, al_s1, al_d1, N);
    agg1_kernel<<<N, 64, 0, stream>>>(rowptr, csr_src, (const uint2*)h1b,
                                      al_s1, al_d1, b1, lnw, lnb,
                                      (uint2*)hmidb, N);
    gemm2_mfma<<<tileBlocks, 256, 0, stream>>>(hmidb, Wp2, as2, ad2, h2b, al_s2, al_d2, N);
    agg2_kernel<<<N, 64, 0, stream>>>(rowptr, csr_src, (const unsigned int*)h2b,
                                      al_s2, al_d2, b2, (float*)d_out, N);
}